// Round 1
// baseline (369.513 us; speedup 1.0000x reference)
//
#include <hip/hip_runtime.h>
#include <math.h>

namespace {
constexpr int kB = 8;
constexpr int kN = 2048;
constexpr int kC = 512;
constexpr int kR = kB * kN;
constexpr float kInvSqrtC = 0.044194173824159216f; // 1/sqrt(512)
}

// A[c,e] = sum_d Wq[d,c] * Wk[d,e]   (both operands K-major over rows d)
__global__ __launch_bounds__(256) void foldA_kernel(
    const float* __restrict__ Wq, const float* __restrict__ Wk, float* __restrict__ A) {
  __shared__ float sq[32][33];  // [k][c]
  __shared__ float sk[32][33];  // [k][e]
  const int c0 = blockIdx.y * 32, e0 = blockIdx.x * 32;
  const int t = threadIdx.x, tc = t & 31, tr = t >> 5;
  float acc[4] = {0.f, 0.f, 0.f, 0.f};
  for (int d0 = 0; d0 < kC; d0 += 32) {
    __syncthreads();
#pragma unroll
    for (int i = 0; i < 4; i++) {
      const int dd = tr + i * 8;
      sq[dd][tc] = Wq[(d0 + dd) * kC + c0 + tc];
      sk[dd][tc] = Wk[(d0 + dd) * kC + e0 + tc];
    }
    __syncthreads();
#pragma unroll
    for (int kk = 0; kk < 32; kk++) {
      const float b = sk[kk][tc];
#pragma unroll
      for (int i = 0; i < 4; i++) acc[i] += sq[kk][tr * 4 + i] * b;
    }
  }
#pragma unroll
  for (int i = 0; i < 4; i++) A[(c0 + tr * 4 + i) * kC + e0 + tc] = acc[i];
}

// M[d,e] = sum_c Wo[d,c] * Wv[c,e]
__global__ __launch_bounds__(256) void foldM_kernel(
    const float* __restrict__ Wo, const float* __restrict__ Wv, float* __restrict__ M) {
  __shared__ float so[32][33];  // [d][k]
  __shared__ float sv[32][33];  // [k][e]
  const int d0 = blockIdx.y * 32, e0 = blockIdx.x * 32;
  const int t = threadIdx.x, tc = t & 31, tr = t >> 5;
  float acc[4] = {0.f, 0.f, 0.f, 0.f};
  for (int c0 = 0; c0 < kC; c0 += 32) {
    __syncthreads();
#pragma unroll
    for (int i = 0; i < 4; i++) {
      const int rr = tr + i * 8;
      so[rr][tc] = Wo[(d0 + rr) * kC + c0 + tc];
      sv[rr][tc] = Wv[(c0 + rr) * kC + e0 + tc];
    }
    __syncthreads();
#pragma unroll
    for (int kk = 0; kk < 32; kk++) {
      const float b = sv[kk][tc];
#pragma unroll
      for (int i = 0; i < 4; i++) acc[i] += so[tr * 4 + i][kk] * b;
    }
  }
#pragma unroll
  for (int i = 0; i < 4; i++) M[(d0 + tr * 4 + i) * kC + e0 + tc] = acc[i];
}

// ubk[c] = sum_d Wq[d,c]*bk[d];  vbq[e] = sum_d Wk[d,e]*bq[d];  bqbk = bq.bk
__global__ __launch_bounds__(256) void foldBias1_kernel(
    const float* __restrict__ Wq, const float* __restrict__ Wk,
    const float* __restrict__ bq, const float* __restrict__ bk,
    float* __restrict__ ubk, float* __restrict__ vbq, float* __restrict__ bqbk) {
  const int c = blockIdx.x * 256 + threadIdx.x;
  float s1 = 0.f, s2 = 0.f;
  for (int d = 0; d < kC; d++) {
    s1 += Wq[d * kC + c] * bk[d];
    s2 += Wk[d * kC + c] * bq[d];
  }
  ubk[c] = s1;
  vbq[c] = s2;
  if (blockIdx.x == 0 && threadIdx.x < 64) {
    float a = 0.f;
#pragma unroll
    for (int it = 0; it < 8; it++) a += bq[it * 64 + threadIdx.x] * bk[it * 64 + threadIdx.x];
#pragma unroll
    for (int off = 32; off; off >>= 1) a += __shfl_xor(a, off);
    if (threadIdx.x == 0) bqbk[0] = a;
  }
}

// bvo[d] = sum_c Wo[d,c]*bv[c]   (wave per row)
__global__ __launch_bounds__(256) void foldBias2_kernel(
    const float* __restrict__ Wo, const float* __restrict__ bv, float* __restrict__ bvo) {
  const int wid = threadIdx.x >> 6, lane = threadIdx.x & 63;
  const int d = blockIdx.x * 4 + wid;
  float a = 0.f;
#pragma unroll
  for (int it = 0; it < 8; it++) a += Wo[d * kC + it * 64 + lane] * bv[it * 64 + lane];
#pragma unroll
  for (int off = 32; off; off >>= 1) a += __shfl_xor(a, off);
  if (lane == 0) bvo[d] = a;
}

__global__ __launch_bounds__(256) void cnt_kernel(const int* __restrict__ nbr, int* __restrict__ cnt) {
  const int n = blockIdx.x * 256 + threadIdx.x;
  if (n < kN) atomicAdd(&cnt[nbr[n]], 1);
}

// Fused: w[r,c] = sum_e x[r,e]*A[c,e] (+ubk[c]);  vo[r,c] = sum_e x[r,e]*M[c,e] (+bvo[c])
__global__ __launch_bounds__(256) void gemm2_kernel(
    const float* __restrict__ x, const float* __restrict__ A, const float* __restrict__ M,
    const float* __restrict__ ubk, const float* __restrict__ bvo,
    float* __restrict__ wbuf, float* __restrict__ vobuf) {
  __shared__ float xs[16][68];   // [k][r]
  __shared__ float as_[16][68];  // [k][c]
  __shared__ float ms_[16][68];  // [k][c]
  const int r0 = blockIdx.y * 64;
  const int c0 = blockIdx.x * 64;
  const int t = threadIdx.x;
  const int tx = t & 15, ty = t >> 4;
  const int lr = t >> 2;        // 0..63
  const int lk = (t & 3) * 4;   // 0,4,8,12
  float accw[4][4] = {};
  float accv[4][4] = {};
  for (int k0 = 0; k0 < kC; k0 += 16) {
    const float4 vx = *reinterpret_cast<const float4*>(&x[(size_t)(r0 + lr) * kC + k0 + lk]);
    const float4 va = *reinterpret_cast<const float4*>(&A[(c0 + lr) * kC + k0 + lk]);
    const float4 vm = *reinterpret_cast<const float4*>(&M[(c0 + lr) * kC + k0 + lk]);
    __syncthreads();
    xs[lk + 0][lr] = vx.x; xs[lk + 1][lr] = vx.y; xs[lk + 2][lr] = vx.z; xs[lk + 3][lr] = vx.w;
    as_[lk + 0][lr] = va.x; as_[lk + 1][lr] = va.y; as_[lk + 2][lr] = va.z; as_[lk + 3][lr] = va.w;
    ms_[lk + 0][lr] = vm.x; ms_[lk + 1][lr] = vm.y; ms_[lk + 2][lr] = vm.z; ms_[lk + 3][lr] = vm.w;
    __syncthreads();
#pragma unroll
    for (int kk = 0; kk < 16; kk++) {
      const float4 av = *reinterpret_cast<const float4*>(&xs[kk][ty * 4]);
      const float4 bw = *reinterpret_cast<const float4*>(&as_[kk][tx * 4]);
      const float4 bm = *reinterpret_cast<const float4*>(&ms_[kk][tx * 4]);
      const float aa[4] = {av.x, av.y, av.z, av.w};
      const float wwv[4] = {bw.x, bw.y, bw.z, bw.w};
      const float mmv[4] = {bm.x, bm.y, bm.z, bm.w};
#pragma unroll
      for (int i = 0; i < 4; i++)
#pragma unroll
        for (int j = 0; j < 4; j++) {
          accw[i][j] += aa[i] * wwv[j];
          accv[i][j] += aa[i] * mmv[j];
        }
    }
  }
  float ub[4], bvv[4];
#pragma unroll
  for (int j = 0; j < 4; j++) {
    ub[j] = ubk[c0 + tx * 4 + j];
    bvv[j] = bvo[c0 + tx * 4 + j];
  }
#pragma unroll
  for (int i = 0; i < 4; i++) {
    const size_t row = (size_t)(r0 + ty * 4 + i);
    float4 ow, ov;
    ow.x = accw[i][0] + ub[0]; ow.y = accw[i][1] + ub[1];
    ow.z = accw[i][2] + ub[2]; ow.w = accw[i][3] + ub[3];
    ov.x = accv[i][0] + bvv[0]; ov.y = accv[i][1] + bvv[1];
    ov.z = accv[i][2] + bvv[2]; ov.w = accv[i][3] + bvv[3];
    *reinterpret_cast<float4*>(&wbuf[row * kC + c0 + tx * 4]) = ow;
    *reinterpret_cast<float4*>(&vobuf[row * kC + c0 + tx * 4]) = ov;
  }
}

// g[r] = dot(x[r,:], vbq)
__global__ __launch_bounds__(256) void g_kernel(
    const float* __restrict__ x, const float* __restrict__ vbq, float* __restrict__ g) {
  const int wid = threadIdx.x >> 6, lane = threadIdx.x & 63;
  const int r = blockIdx.x * 4 + wid;
  const float4* xr = reinterpret_cast<const float4*>(x + (size_t)r * kC);
  const float4* q4 = reinterpret_cast<const float4*>(vbq);
  float a = 0.f;
#pragma unroll
  for (int it = 0; it < 2; it++) {
    const float4 u = xr[it * 64 + lane];
    const float4 v = q4[it * 64 + lane];
    a += u.x * v.x + u.y * v.y + u.z * v.z + u.w * v.w;
  }
#pragma unroll
  for (int off = 32; off; off >>= 1) a += __shfl_xor(a, off);
  if (lane == 0) g[r] = a;
}

// part[b,jc,d] = sum_{j in chunk} cnt[j]*vo[b,j,d]
__global__ __launch_bounds__(256) void svo_part_kernel(
    const float* __restrict__ vo, const int* __restrict__ cnt, float* __restrict__ part) {
  const int d = blockIdx.x * 256 + threadIdx.x;  // gridDim.x = 2
  const int jc = blockIdx.y;                     // 32
  const int b = blockIdx.z;                      // 8
  float a = 0.f;
  for (int j = jc * 64; j < jc * 64 + 64; j++) {
    const int cj = cnt[j];
    if (cj) a += (float)cj * vo[((size_t)(b * kN + j)) * kC + d];
  }
  part[(size_t)(b * 32 + jc) * kC + d] = a;
}

__global__ __launch_bounds__(256) void svo_reduce_kernel(
    const float* __restrict__ part, float* __restrict__ svo) {
  const int d = blockIdx.x * 256 + threadIdx.x;
  const int b = blockIdx.y;
  float a = 0.f;
#pragma unroll
  for (int jc = 0; jc < 32; jc++) a += part[(size_t)(b * 32 + jc) * kC + d];
  svo[b * kC + d] = a;
}

// Per (b,n): s = x_n . w'[b,j] + g[b,j] + bqbk + rb;  out = inv*SVO + coef*VO[j2] + bo
__global__ __launch_bounds__(256) void final_kernel(
    const float* __restrict__ x, const float* __restrict__ wbuf, const float* __restrict__ vo,
    const float* __restrict__ svo, const float* __restrict__ g, const int* __restrict__ nbr,
    const float* __restrict__ bqbk, const float* __restrict__ rb, const float* __restrict__ bo,
    float* __restrict__ out) {
  const int wid = threadIdx.x >> 6, lane = threadIdx.x & 63;
  const int rg = blockIdx.x * 4 + wid;   // 0..kR-1
  const int b = rg >> 11, n = rg & (kN - 1);
  const int j = nbr[n];
  const int j2 = nbr[j];
  const float4* xr = reinterpret_cast<const float4*>(x + (size_t)rg * kC);
  const float4* wr = reinterpret_cast<const float4*>(wbuf + (size_t)(b * kN + j) * kC);
  float a = 0.f;
#pragma unroll
  for (int it = 0; it < 2; it++) {
    const float4 u = xr[it * 64 + lane];
    const float4 v = wr[it * 64 + lane];
    a += u.x * v.x + u.y * v.y + u.z * v.z + u.w * v.w;
  }
#pragma unroll
  for (int off = 32; off; off >>= 1) a += __shfl_xor(a, off);
  const float s = a + g[b * kN + j] + bqbk[0] + rb[0];
  const float t = s * kInvSqrtC;
  const float e = expf(t);
  const float inv = 1.0f / (e + (float)(kN - 1));
  const float coef = (e - 1.0f) * inv;
  const float4* vr = reinterpret_cast<const float4*>(vo + (size_t)(b * kN + j2) * kC);
  const float4* sv = reinterpret_cast<const float4*>(svo + b * kC);
  const float4* bo4 = reinterpret_cast<const float4*>(bo);
  float4* o4 = reinterpret_cast<float4*>(out + (size_t)rg * kC);
#pragma unroll
  for (int it = 0; it < 2; it++) {
    const int idx = it * 64 + lane;
    const float4 vv = vr[idx], ss = sv[idx], bb = bo4[idx];
    float4 r;
    r.x = ss.x * inv + vv.x * coef + bb.x;
    r.y = ss.y * inv + vv.y * coef + bb.y;
    r.z = ss.z * inv + vv.z * coef + bb.z;
    r.w = ss.w * inv + vv.w * coef + bb.w;
    o4[idx] = r;
  }
}

extern "C" void kernel_launch(void* const* d_in, const int* in_sizes, int n_in,
                              void* d_out, int out_size, void* d_ws, size_t ws_size,
                              hipStream_t stream) {
  const float* x  = (const float*)d_in[0];
  const int* nbr  = (const int*)d_in[1];
  const float* Wq = (const float*)d_in[2];
  const float* bq = (const float*)d_in[3];
  const float* Wk = (const float*)d_in[4];
  const float* bk = (const float*)d_in[5];
  const float* Wv = (const float*)d_in[6];
  const float* bv = (const float*)d_in[7];
  const float* rb = (const float*)d_in[8];
  const float* Wo = (const float*)d_in[9];
  const float* bo = (const float*)d_in[10];
  float* out = (float*)d_out;

  char* ws = (char*)d_ws;
  size_t off = 0;
  auto alloc = [&](size_t bytes) -> void* {
    void* p = ws + off;
    off = (off + bytes + 255) & ~(size_t)255;
    return p;
  };
  float* A    = (float*)alloc((size_t)kC * kC * 4);
  float* M    = (float*)alloc((size_t)kC * kC * 4);
  float* ubk  = (float*)alloc(kC * 4);
  float* vbq  = (float*)alloc(kC * 4);
  float* bvo  = (float*)alloc(kC * 4);
  float* bqbk = (float*)alloc(4);
  int*   cnt  = (int*)alloc(kN * 4);
  float* g    = (float*)alloc((size_t)kR * 4);
  float* svo  = (float*)alloc((size_t)kB * kC * 4);
  float* part = (float*)alloc((size_t)kB * 32 * kC * 4);
  float* wbuf = (float*)alloc((size_t)kR * kC * 4);
  float* vobf = (float*)alloc((size_t)kR * kC * 4);
  (void)ws_size; (void)n_in; (void)in_sizes; (void)out_size;

  hipMemsetAsync(cnt, 0, kN * sizeof(int), stream);
  foldA_kernel<<<dim3(16, 16), 256, 0, stream>>>(Wq, Wk, A);
  foldM_kernel<<<dim3(16, 16), 256, 0, stream>>>(Wo, Wv, M);
  foldBias1_kernel<<<2, 256, 0, stream>>>(Wq, Wk, bq, bk, ubk, vbq, bqbk);
  foldBias2_kernel<<<128, 256, 0, stream>>>(Wo, bv, bvo);
  cnt_kernel<<<8, 256, 0, stream>>>(nbr, cnt);
  gemm2_kernel<<<dim3(8, 256), 256, 0, stream>>>(x, A, M, ubk, bvo, wbuf, vobf);
  g_kernel<<<kR / 4, 256, 0, stream>>>(x, vbq, g);
  svo_part_kernel<<<dim3(2, 32, kB), 256, 0, stream>>>(vobf, cnt, part);
  svo_reduce_kernel<<<dim3(2, kB), 256, 0, stream>>>(part, svo);
  final_kernel<<<kR / 4, 256, 0, stream>>>(x, wbuf, vobf, svo, g, nbr, bqbk, rb, bo, out);
}

// Round 2
// 164.954 us; speedup vs baseline: 2.2401x; 2.2401x over previous
//
#include <hip/hip_runtime.h>
#include <hip/hip_bf16.h>
#include <math.h>

namespace {
constexpr int kB = 8;
constexpr int kN = 2048;
constexpr int kC = 512;
constexpr int kR = kB * kN;          // 16384 rows total
constexpr int kNC = 2 * kC;          // 1024 concatenated output cols
constexpr float kInvSqrtC = 0.044194173824159216f; // 1/sqrt(512)

typedef __attribute__((ext_vector_type(8))) short short8;
typedef __attribute__((ext_vector_type(4))) float f32x4;
typedef unsigned short ushort;
}

static __device__ __forceinline__ float bf2f(ushort u) {
  union { unsigned int i; float f; } v; v.i = (unsigned int)u << 16; return v.f;
}
static __device__ __forceinline__ ushort f2bf(float f) {
  __hip_bfloat16 h = __float2bfloat16(f);
  union { __hip_bfloat16 h; ushort u; } cv; cv.h = h; return cv.u;
}

#define GLOAD16(G, L) __builtin_amdgcn_global_load_lds( \
    (const __attribute__((address_space(1))) unsigned int*)(G), \
    (__attribute__((address_space(3))) unsigned int*)(L), 16, 0, 0)

// ---------- x (fp32) -> xh (bf16) ----------
__global__ __launch_bounds__(256) void cast_kernel(
    const float* __restrict__ x, ushort* __restrict__ xh) {
  const size_t i = (size_t)blockIdx.x * 256 + threadIdx.x;  // 8 elems / thread
  const float4 a = *reinterpret_cast<const float4*>(&x[i * 8]);
  const float4 b = *reinterpret_cast<const float4*>(&x[i * 8 + 4]);
  short8 o;
  o[0] = (short)f2bf(a.x); o[1] = (short)f2bf(a.y);
  o[2] = (short)f2bf(a.z); o[3] = (short)f2bf(a.w);
  o[4] = (short)f2bf(b.x); o[5] = (short)f2bf(b.y);
  o[6] = (short)f2bf(b.z); o[7] = (short)f2bf(b.w);
  *reinterpret_cast<short8*>(&xh[i * 8]) = o;
}

// ---------- A[c,e] = sum_d Wq[d,c]*Wk[d,e] -> Bh rows [0,512) ----------
__global__ __launch_bounds__(256) void foldA_kernel(
    const float* __restrict__ Wq, const float* __restrict__ Wk, ushort* __restrict__ Bh) {
  __shared__ float sq[32][33];
  __shared__ float sk[32][33];
  const int c0 = blockIdx.y * 32, e0 = blockIdx.x * 32;
  const int t = threadIdx.x, tc = t & 31, tr = t >> 5;
  float acc[4] = {0.f, 0.f, 0.f, 0.f};
  for (int d0 = 0; d0 < kC; d0 += 32) {
    __syncthreads();
#pragma unroll
    for (int i = 0; i < 4; i++) {
      const int dd = tr + i * 8;
      sq[dd][tc] = Wq[(d0 + dd) * kC + c0 + tc];
      sk[dd][tc] = Wk[(d0 + dd) * kC + e0 + tc];
    }
    __syncthreads();
#pragma unroll
    for (int kk = 0; kk < 32; kk++) {
      const float b = sk[kk][tc];
#pragma unroll
      for (int i = 0; i < 4; i++) acc[i] += sq[kk][tr * 4 + i] * b;
    }
  }
#pragma unroll
  for (int i = 0; i < 4; i++) Bh[(c0 + tr * 4 + i) * kC + e0 + tc] = f2bf(acc[i]);
}

// ---------- M[d,e] = sum_c Wo[d,c]*Wv[c,e] -> Bh rows [512,1024) ----------
__global__ __launch_bounds__(256) void foldM_kernel(
    const float* __restrict__ Wo, const float* __restrict__ Wv, ushort* __restrict__ Bh) {
  __shared__ float so[32][33];
  __shared__ float sv[32][33];
  const int d0 = blockIdx.y * 32, e0 = blockIdx.x * 32;
  const int t = threadIdx.x, tc = t & 31, tr = t >> 5;
  float acc[4] = {0.f, 0.f, 0.f, 0.f};
  for (int c0 = 0; c0 < kC; c0 += 32) {
    __syncthreads();
#pragma unroll
    for (int i = 0; i < 4; i++) {
      const int rr = tr + i * 8;
      so[rr][tc] = Wo[(d0 + rr) * kC + c0 + tc];
      sv[rr][tc] = Wv[(c0 + rr) * kC + e0 + tc];
    }
    __syncthreads();
#pragma unroll
    for (int kk = 0; kk < 32; kk++) {
      const float b = sv[kk][tc];
#pragma unroll
      for (int i = 0; i < 4; i++) acc[i] += so[tr * 4 + i][kk] * b;
    }
  }
#pragma unroll
  for (int i = 0; i < 4; i++) Bh[(kC + d0 + tr * 4 + i) * kC + e0 + tc] = f2bf(acc[i]);
}

// ---------- bias folds: partial over 32-row slices, coalesced ----------
__global__ __launch_bounds__(256) void bias1_part_kernel(
    const float* __restrict__ Wq, const float* __restrict__ Wk,
    const float* __restrict__ bq, const float* __restrict__ bk,
    float* __restrict__ pU, float* __restrict__ pV) {
  const int c = blockIdx.x * 256 + threadIdx.x;
  const int d0 = blockIdx.y * 32;
  float s1 = 0.f, s2 = 0.f;
  for (int d = d0; d < d0 + 32; d++) {
    s1 += Wq[d * kC + c] * bk[d];
    s2 += Wk[d * kC + c] * bq[d];
  }
  pU[blockIdx.y * kC + c] = s1;
  pV[blockIdx.y * kC + c] = s2;
}

__global__ __launch_bounds__(256) void bias1_red_kernel(
    const float* __restrict__ pU, const float* __restrict__ pV,
    const float* __restrict__ bq, const float* __restrict__ bk,
    float* __restrict__ biascat, float* __restrict__ vbq, float* __restrict__ bqbk) {
  const int c = blockIdx.x * 256 + threadIdx.x;
  float s1 = 0.f, s2 = 0.f;
#pragma unroll
  for (int p = 0; p < 16; p++) {
    s1 += pU[p * kC + c];
    s2 += pV[p * kC + c];
  }
  biascat[c] = s1;   // ubk
  vbq[c] = s2;
  if (blockIdx.x == 0 && threadIdx.x < 64) {
    float a = 0.f;
#pragma unroll
    for (int it = 0; it < 8; it++) a += bq[it * 64 + threadIdx.x] * bk[it * 64 + threadIdx.x];
#pragma unroll
    for (int off = 32; off; off >>= 1) a += __shfl_xor(a, off);
    if (threadIdx.x == 0) bqbk[0] = a;
  }
}

// bvo[d] = sum_c Wo[d,c]*bv[c]  -> biascat[512+d]
__global__ __launch_bounds__(256) void foldBias2_kernel(
    const float* __restrict__ Wo, const float* __restrict__ bv, float* __restrict__ biascat) {
  const int wid = threadIdx.x >> 6, lane = threadIdx.x & 63;
  const int d = blockIdx.x * 4 + wid;
  float a = 0.f;
#pragma unroll
  for (int it = 0; it < 8; it++) a += Wo[d * kC + it * 64 + lane] * bv[it * 64 + lane];
#pragma unroll
  for (int off = 32; off; off >>= 1) a += __shfl_xor(a, off);
  if (lane == 0) biascat[kC + d] = a;
}

__global__ __launch_bounds__(256) void cnt_kernel(const int* __restrict__ nbr, int* __restrict__ cnt) {
  const int n = blockIdx.x * 256 + threadIdx.x;
  if (n < kN) atomicAdd(&cnt[nbr[n]], 1);
}

// ---------- big fused GEMM: obuf[r, 0:512] = w = xh@A^T (+ubk),
// ----------                 obuf[r, 512:1024] = vo = xh@M^T (+bvo) ----------
__global__ __launch_bounds__(256) void mm_kernel(
    const ushort* __restrict__ xh, const ushort* __restrict__ Bh,
    const float* __restrict__ biascat, ushort* __restrict__ obuf) {
  __shared__ ushort lA[128 * 64];
  __shared__ ushort lB[128 * 64];
  // XCD-aware swizzle: 1024 % 8 == 0, XCD k gets orig ids [k*128,(k+1)*128)
  const int id = blockIdx.x;
  const int orig = (id & 7) * 128 + (id >> 3);
  const int r0 = (orig >> 3) * 128;          // 128 row-tiles
  const int c0 = (orig & 7) * 128;           // 8 col-tiles over 1024
  const int t = threadIdx.x;
  const int lane = t & 63, w = t >> 6;
  const int wr = (w >> 1) * 64, wc = (w & 1) * 64;
  const int srow = t >> 3, scol = (t & 7) * 8;   // staging: 16B per thread, linear lane order
  f32x4 acc[4][4] = {};
  for (int k0 = 0; k0 < kC; k0 += 64) {
#pragma unroll
    for (int it = 0; it < 4; it++) {
      GLOAD16(&xh[(size_t)(r0 + it * 32 + srow) * kC + k0 + scol], &lA[(it * 32 + srow) * 64 + scol]);
      GLOAD16(&Bh[(size_t)(c0 + it * 32 + srow) * kC + k0 + scol], &lB[(it * 32 + srow) * 64 + scol]);
    }
    __syncthreads();   // drains vmcnt before barrier
#pragma unroll
    for (int kk = 0; kk < 2; kk++) {
      const int ko = kk * 32 + (lane >> 4) * 8;
      short8 af[4], bfr[4];
#pragma unroll
      for (int i = 0; i < 4; i++)
        af[i] = *reinterpret_cast<const short8*>(&lA[(wr + i * 16 + (lane & 15)) * 64 + ko]);
#pragma unroll
      for (int j = 0; j < 4; j++)
        bfr[j] = *reinterpret_cast<const short8*>(&lB[(wc + j * 16 + (lane & 15)) * 64 + ko]);
#pragma unroll
      for (int i = 0; i < 4; i++)
#pragma unroll
        for (int j = 0; j < 4; j++)
          acc[i][j] = __builtin_amdgcn_mfma_f32_16x16x32_bf16(af[i], bfr[j], acc[i][j], 0, 0, 0);
    }
    __syncthreads();   // all waves done reading before restage
  }
#pragma unroll
  for (int j = 0; j < 4; j++) {
    const int col = c0 + wc + j * 16 + (lane & 15);
    const float bias = biascat[col];
#pragma unroll
    for (int i = 0; i < 4; i++) {
      const int rbase = r0 + wr + i * 16 + (lane >> 4) * 4;
#pragma unroll
      for (int q = 0; q < 4; q++)
        obuf[(size_t)(rbase + q) * kNC + col] = f2bf(acc[i][j][q] + bias);
    }
  }
}

// ---------- g[r] = dot(xh[r,:], vbq) ----------
__global__ __launch_bounds__(256) void g_kernel(
    const ushort* __restrict__ xh, const float* __restrict__ vbq, float* __restrict__ g) {
  const int wid = threadIdx.x >> 6, lane = threadIdx.x & 63;
  const int r = blockIdx.x * 4 + wid;
  const short8 u = *reinterpret_cast<const short8*>(&xh[(size_t)r * kC + lane * 8]);
  const float4 v0 = *reinterpret_cast<const float4*>(&vbq[lane * 8]);
  const float4 v1 = *reinterpret_cast<const float4*>(&vbq[lane * 8 + 4]);
  float a = bf2f((ushort)u[0]) * v0.x + bf2f((ushort)u[1]) * v0.y +
            bf2f((ushort)u[2]) * v0.z + bf2f((ushort)u[3]) * v0.w +
            bf2f((ushort)u[4]) * v1.x + bf2f((ushort)u[5]) * v1.y +
            bf2f((ushort)u[6]) * v1.z + bf2f((ushort)u[7]) * v1.w;
#pragma unroll
  for (int off = 32; off; off >>= 1) a += __shfl_xor(a, off);
  if (lane == 0) g[r] = a;
}

// ---------- part[b,jc,d] = sum_{j in chunk} cnt[j]*vo[b,j,d] ----------
__global__ __launch_bounds__(256) void svo_part_kernel(
    const ushort* __restrict__ obuf, const int* __restrict__ cnt, float* __restrict__ part) {
  const int d = blockIdx.x * 256 + threadIdx.x;  // 2 blocks
  const int jc = blockIdx.y;                     // 32
  const int b = blockIdx.z;                      // 8
  float a = 0.f;
  for (int j = jc * 64; j < jc * 64 + 64; j++) {
    const int cj = cnt[j];
    if (cj) a += (float)cj * bf2f(obuf[(size_t)(b * kN + j) * kNC + kC + d]);
  }
  part[(size_t)(b * 32 + jc) * kC + d] = a;
}

__global__ __launch_bounds__(256) void svo_reduce_kernel(
    const float* __restrict__ part, float* __restrict__ svo) {
  const int d = blockIdx.x * 256 + threadIdx.x;
  const int b = blockIdx.y;
  float a = 0.f;
#pragma unroll
  for (int jc = 0; jc < 32; jc++) a += part[(size_t)(b * 32 + jc) * kC + d];
  svo[b * kC + d] = a;
}

// ---------- final: s = xh_n . w_j + g_j + bqbk + rb; out = inv*SVO + coef*VO[j2] + bo ----------
__global__ __launch_bounds__(256) void final_kernel(
    const ushort* __restrict__ xh, const ushort* __restrict__ obuf,
    const float* __restrict__ svo, const float* __restrict__ g, const int* __restrict__ nbr,
    const float* __restrict__ bqbk, const float* __restrict__ rb, const float* __restrict__ bo,
    float* __restrict__ out) {
  const int wid = threadIdx.x >> 6, lane = threadIdx.x & 63;
  const int rg = blockIdx.x * 4 + wid;
  const int b = rg >> 11, n = rg & (kN - 1);
  const int j = nbr[n];
  const int j2 = nbr[j];
  const short8 xv = *reinterpret_cast<const short8*>(&xh[(size_t)rg * kC + lane * 8]);
  const short8 wv = *reinterpret_cast<const short8*>(&obuf[(size_t)(b * kN + j) * kNC + lane * 8]);
  float a = 0.f;
#pragma unroll
  for (int q = 0; q < 8; q++) a += bf2f((ushort)xv[q]) * bf2f((ushort)wv[q]);
#pragma unroll
  for (int off = 32; off; off >>= 1) a += __shfl_xor(a, off);
  const float s = a + g[b * kN + j] + bqbk[0] + rb[0];
  const float tt = s * kInvSqrtC;
  const float e = expf(tt);
  const float inv = 1.0f / (e + (float)(kN - 1));
  const float coef = (e - 1.0f) * inv;
  const short8 vv = *reinterpret_cast<const short8*>(&obuf[(size_t)(b * kN + j2) * kNC + kC + lane * 8]);
  const float4 s0 = *reinterpret_cast<const float4*>(&svo[b * kC + lane * 8]);
  const float4 s1 = *reinterpret_cast<const float4*>(&svo[b * kC + lane * 8 + 4]);
  const float4 b0 = *reinterpret_cast<const float4*>(&bo[lane * 8]);
  const float4 b1 = *reinterpret_cast<const float4*>(&bo[lane * 8 + 4]);
  float4 r0, r1;
  r0.x = s0.x * inv + bf2f((ushort)vv[0]) * coef + b0.x;
  r0.y = s0.y * inv + bf2f((ushort)vv[1]) * coef + b0.y;
  r0.z = s0.z * inv + bf2f((ushort)vv[2]) * coef + b0.z;
  r0.w = s0.w * inv + bf2f((ushort)vv[3]) * coef + b0.w;
  r1.x = s1.x * inv + bf2f((ushort)vv[4]) * coef + b1.x;
  r1.y = s1.y * inv + bf2f((ushort)vv[5]) * coef + b1.y;
  r1.z = s1.z * inv + bf2f((ushort)vv[6]) * coef + b1.z;
  r1.w = s1.w * inv + bf2f((ushort)vv[7]) * coef + b1.w;
  *reinterpret_cast<float4*>(&out[(size_t)rg * kC + lane * 8]) = r0;
  *reinterpret_cast<float4*>(&out[(size_t)rg * kC + lane * 8 + 4]) = r1;
}

extern "C" void kernel_launch(void* const* d_in, const int* in_sizes, int n_in,
                              void* d_out, int out_size, void* d_ws, size_t ws_size,
                              hipStream_t stream) {
  const float* x  = (const float*)d_in[0];
  const int* nbr  = (const int*)d_in[1];
  const float* Wq = (const float*)d_in[2];
  const float* bq = (const float*)d_in[3];
  const float* Wk = (const float*)d_in[4];
  const float* bk = (const float*)d_in[5];
  const float* Wv = (const float*)d_in[6];
  const float* bv = (const float*)d_in[7];
  const float* rb = (const float*)d_in[8];
  const float* Wo = (const float*)d_in[9];
  const float* bo = (const float*)d_in[10];
  float* out = (float*)d_out;

  char* ws = (char*)d_ws;
  size_t off = 0;
  auto alloc = [&](size_t bytes) -> void* {
    void* p = ws + off;
    off = (off + bytes + 255) & ~(size_t)255;
    return p;
  };
  ushort* xh    = (ushort*)alloc((size_t)kR * kC * 2);
  ushort* Bh    = (ushort*)alloc((size_t)kNC * kC * 2);
  ushort* obuf  = (ushort*)alloc((size_t)kR * kNC * 2);
  float* biascat = (float*)alloc(kNC * 4);
  float* vbq    = (float*)alloc(kC * 4);
  float* bqbk   = (float*)alloc(4);
  int*   cnt    = (int*)alloc(kN * 4);
  float* g      = (float*)alloc((size_t)kR * 4);
  float* svo    = (float*)alloc((size_t)kB * kC * 4);
  float* part   = (float*)alloc((size_t)kB * 32 * kC * 4);
  float* pU     = (float*)alloc((size_t)16 * kC * 4);
  float* pV     = (float*)alloc((size_t)16 * kC * 4);
  (void)ws_size; (void)n_in; (void)in_sizes; (void)out_size;

  hipMemsetAsync(cnt, 0, kN * sizeof(int), stream);
  cast_kernel<<<kR * kC / (256 * 8), 256, 0, stream>>>(x, xh);
  foldA_kernel<<<dim3(16, 16), 256, 0, stream>>>(Wq, Wk, Bh);
  foldM_kernel<<<dim3(16, 16), 256, 0, stream>>>(Wo, Wv, Bh);
  bias1_part_kernel<<<dim3(2, 16), 256, 0, stream>>>(Wq, Wk, bq, bk, pU, pV);
  bias1_red_kernel<<<2, 256, 0, stream>>>(pU, pV, bq, bk, biascat, vbq, bqbk);
  foldBias2_kernel<<<128, 256, 0, stream>>>(Wo, bv, biascat);
  cnt_kernel<<<8, 256, 0, stream>>>(nbr, cnt);
  mm_kernel<<<1024, 256, 0, stream>>>(xh, Bh, biascat, obuf);
  g_kernel<<<kR / 4, 256, 0, stream>>>(xh, vbq, g);
  svo_part_kernel<<<dim3(2, 32, kB), 256, 0, stream>>>(obuf, cnt, part);
  svo_reduce_kernel<<<dim3(2, kB), 256, 0, stream>>>(part, svo);
  final_kernel<<<kR / 4, 256, 0, stream>>>(xh, obuf, svo, g, nbr, bqbk, rb, bo, out);
}

// Round 3
// 94.892 us; speedup vs baseline: 3.8940x; 1.7383x over previous
//
#include <hip/hip_runtime.h>
#include <hip/hip_bf16.h>
#include <math.h>

namespace {
constexpr int kB = 8;
constexpr int kN = 2048;
constexpr int kC = 512;
constexpr int kR = kB * kN;          // 16384 rows total
constexpr int kNC = 2 * kC;          // 1024 concatenated output cols
constexpr float kInvSqrtC = 0.044194173824159216f; // 1/sqrt(512)

typedef __attribute__((ext_vector_type(8))) short short8;
typedef __attribute__((ext_vector_type(4))) short short4b;
typedef __attribute__((ext_vector_type(4))) float f32x4;
typedef unsigned short ushort;
}

static __device__ __forceinline__ float bf2f(ushort u) {
  union { unsigned int i; float f; } v; v.i = (unsigned int)u << 16; return v.f;
}
static __device__ __forceinline__ ushort f2bf(float f) {
  __hip_bfloat16 h = __float2bfloat16(f);
  union { __hip_bfloat16 h; ushort u; } cv; cv.h = h; return cv.u;
}

#define GLOAD16(G, L) __builtin_amdgcn_global_load_lds( \
    (const __attribute__((address_space(1))) unsigned int*)(G), \
    (__attribute__((address_space(3))) unsigned int*)(L), 16, 0, 0)

// ---------- x (fp32) -> xh (bf16), plus neighbor-count histogram ----------
__global__ __launch_bounds__(256) void cast_kernel(
    const float* __restrict__ x, ushort* __restrict__ xh,
    const int* __restrict__ nbr, int* __restrict__ cnt) {
  const size_t i = (size_t)blockIdx.x * 256 + threadIdx.x;  // 8 elems / thread
  const float4 a = *reinterpret_cast<const float4*>(&x[i * 8]);
  const float4 b = *reinterpret_cast<const float4*>(&x[i * 8 + 4]);
  short8 o;
  o[0] = (short)f2bf(a.x); o[1] = (short)f2bf(a.y);
  o[2] = (short)f2bf(a.z); o[3] = (short)f2bf(a.w);
  o[4] = (short)f2bf(b.x); o[5] = (short)f2bf(b.y);
  o[6] = (short)f2bf(b.z); o[7] = (short)f2bf(b.w);
  *reinterpret_cast<short8*>(&xh[i * 8]) = o;
  if (blockIdx.x < 8) {
    const int n = blockIdx.x * 256 + threadIdx.x;  // < 2048
    atomicAdd(&cnt[nbr[n]], 1);
  }
}

// ---------- weights fp32 -> bf16 (3 transposed + 1 straight) ----------
// z=0: WqT[c][d]=Wq[d][c]; z=1: WkT[e][d]=Wk[d][e]; z=2: WvT[e][c]=Wv[c][e]; z=3: Woh=Wo
__global__ __launch_bounds__(256) void castw_kernel(
    const float* __restrict__ Wq, const float* __restrict__ Wk,
    const float* __restrict__ Wv, const float* __restrict__ Wo,
    ushort* __restrict__ WqT, ushort* __restrict__ WkT,
    ushort* __restrict__ WvT, ushort* __restrict__ Woh) {
  const int z = blockIdx.z;
  const int d0 = blockIdx.x * 64, c0 = blockIdx.y * 64;
  const int t = threadIdx.x;
  if (z == 3) {
#pragma unroll
    for (int i = 0; i < 4; i++) {
      const int row = i * 16 + (t >> 4), col4 = (t & 15) * 4;
      const float4 v = *reinterpret_cast<const float4*>(&Wo[(d0 + row) * kC + c0 + col4]);
      short4b o;
      o[0] = (short)f2bf(v.x); o[1] = (short)f2bf(v.y);
      o[2] = (short)f2bf(v.z); o[3] = (short)f2bf(v.w);
      *reinterpret_cast<short4b*>(&Woh[(d0 + row) * kC + c0 + col4]) = o;
    }
    return;
  }
  __shared__ float ld[64][65];
  const float* S = (z == 0) ? Wq : ((z == 1) ? Wk : Wv);
  ushort* T = (z == 0) ? WqT : ((z == 1) ? WkT : WvT);
#pragma unroll
  for (int i = 0; i < 4; i++) {
    const int dl = i * 16 + (t >> 4), cl4 = (t & 15) * 4;
    const float4 v = *reinterpret_cast<const float4*>(&S[(d0 + dl) * kC + c0 + cl4]);
    ld[dl][cl4 + 0] = v.x; ld[dl][cl4 + 1] = v.y;
    ld[dl][cl4 + 2] = v.z; ld[dl][cl4 + 3] = v.w;
  }
  __syncthreads();
#pragma unroll
  for (int i = 0; i < 4; i++) {
    const int cl = i * 16 + (t >> 4), dl4 = (t & 15) * 4;
    short4b o;
#pragma unroll
    for (int q = 0; q < 4; q++) o[q] = (short)f2bf(ld[dl4 + q][cl]);
    *reinterpret_cast<short4b*>(&T[(size_t)(c0 + cl) * kC + d0 + dl4]) = o;
  }
}

// ---------- MFMA fold: z=0 -> Bh[0:512) = A = WqT @ WkT^T ; z=1 -> Bh[512:1024) = M = Wo @ WvT^T ----------
__global__ __launch_bounds__(256) void fold_kernel(
    const ushort* __restrict__ WqT, const ushort* __restrict__ WkT,
    const ushort* __restrict__ Woh, const ushort* __restrict__ WvT,
    ushort* __restrict__ Bh) {
  __shared__ ushort lA[64 * 64];
  __shared__ ushort lB[64 * 64];
  const int z = blockIdx.z;
  const ushort* Ap = z ? Woh : WqT;
  const ushort* Bp = z ? WvT : WkT;
  const int r0 = blockIdx.y * 64, c0 = blockIdx.x * 64;
  const int t = threadIdx.x, lane = t & 63, w = t >> 6;
  const int wr = (w >> 1) * 32, wc = (w & 1) * 32;
  const int srow = t >> 3, scol = (t & 7) * 8;
  f32x4 acc[2][2] = {};
  for (int k0 = 0; k0 < kC; k0 += 64) {
#pragma unroll
    for (int it = 0; it < 2; it++) {
      GLOAD16(&Ap[(size_t)(r0 + it * 32 + srow) * kC + k0 + scol], &lA[(it * 32 + srow) * 64 + scol]);
      GLOAD16(&Bp[(size_t)(c0 + it * 32 + srow) * kC + k0 + scol], &lB[(it * 32 + srow) * 64 + scol]);
    }
    __syncthreads();
#pragma unroll
    for (int kk = 0; kk < 2; kk++) {
      const int ko = kk * 32 + (lane >> 4) * 8;
      short8 af[2], bfr[2];
#pragma unroll
      for (int i = 0; i < 2; i++)
        af[i] = *reinterpret_cast<const short8*>(&lA[(wr + i * 16 + (lane & 15)) * 64 + ko]);
#pragma unroll
      for (int j = 0; j < 2; j++)
        bfr[j] = *reinterpret_cast<const short8*>(&lB[(wc + j * 16 + (lane & 15)) * 64 + ko]);
#pragma unroll
      for (int i = 0; i < 2; i++)
#pragma unroll
        for (int j = 0; j < 2; j++)
          acc[i][j] = __builtin_amdgcn_mfma_f32_16x16x32_bf16(af[i], bfr[j], acc[i][j], 0, 0, 0);
    }
    __syncthreads();
  }
#pragma unroll
  for (int j = 0; j < 2; j++) {
    const int col = c0 + wc + j * 16 + (lane & 15);
#pragma unroll
    for (int i = 0; i < 2; i++) {
      const int rbase = r0 + wr + i * 16 + (lane >> 4) * 4;
#pragma unroll
      for (int q = 0; q < 4; q++)
        Bh[(size_t)(z * kC + rbase + q) * kC + col] = f2bf(acc[i][j][q]);
    }
  }
}

// ---------- bias folds: wave-per-row bf16 dots ----------
// gid<512: biascat[c]=WqT[c,:].bk ; 512<=gid<1024: vbq[e]=WkT[e,:].bq ; else biascat[512+d]=Woh[d,:].bv
__global__ __launch_bounds__(256) void biasfold_kernel(
    const ushort* __restrict__ WqT, const ushort* __restrict__ WkT, const ushort* __restrict__ Woh,
    const float* __restrict__ bq, const float* __restrict__ bk, const float* __restrict__ bv,
    float* __restrict__ biascat, float* __restrict__ vbq, float* __restrict__ bqbk) {
  const int wid = threadIdx.x >> 6, lane = threadIdx.x & 63;
  const int gid = blockIdx.x * 4 + wid;  // 0..1535
  const ushort* rowp;
  const float* vec;
  if (gid < 512)       { rowp = &WqT[(size_t)gid * kC];          vec = bk; }
  else if (gid < 1024) { rowp = &WkT[(size_t)(gid - 512) * kC];  vec = bq; }
  else                 { rowp = &Woh[(size_t)(gid - 1024) * kC]; vec = bv; }
  const short8 u = *reinterpret_cast<const short8*>(&rowp[lane * 8]);
  const float4 v0 = *reinterpret_cast<const float4*>(&vec[lane * 8]);
  const float4 v1 = *reinterpret_cast<const float4*>(&vec[lane * 8 + 4]);
  float a = bf2f((ushort)u[0]) * v0.x + bf2f((ushort)u[1]) * v0.y +
            bf2f((ushort)u[2]) * v0.z + bf2f((ushort)u[3]) * v0.w +
            bf2f((ushort)u[4]) * v1.x + bf2f((ushort)u[5]) * v1.y +
            bf2f((ushort)u[6]) * v1.z + bf2f((ushort)u[7]) * v1.w;
#pragma unroll
  for (int off = 32; off; off >>= 1) a += __shfl_xor(a, off);
  if (lane == 0) {
    if (gid < 512) biascat[gid] = a;
    else if (gid < 1024) vbq[gid - 512] = a;
    else biascat[gid - 512] = a;
  }
  if (blockIdx.x == 0 && wid == 1) {
    const float4 q0 = *reinterpret_cast<const float4*>(&bq[lane * 8]);
    const float4 q1 = *reinterpret_cast<const float4*>(&bq[lane * 8 + 4]);
    const float4 k0 = *reinterpret_cast<const float4*>(&bk[lane * 8]);
    const float4 k1 = *reinterpret_cast<const float4*>(&bk[lane * 8 + 4]);
    float s = q0.x * k0.x + q0.y * k0.y + q0.z * k0.z + q0.w * k0.w +
              q1.x * k1.x + q1.y * k1.y + q1.z * k1.z + q1.w * k1.w;
#pragma unroll
    for (int off = 32; off; off >>= 1) s += __shfl_xor(s, off);
    if (lane == 0) bqbk[0] = s;
  }
}

// ---------- big fused GEMM: obuf[r, 0:512] = w = xh@A^T (+ubk),
// ----------                 obuf[r, 512:1024] = vo = xh@M^T (+bvo) ----------
__global__ __launch_bounds__(256) void mm_kernel(
    const ushort* __restrict__ xh, const ushort* __restrict__ Bh,
    const float* __restrict__ biascat, ushort* __restrict__ obuf) {
  __shared__ ushort lA[128 * 64];
  __shared__ ushort lB[128 * 64];
  const int id = blockIdx.x;
  const int orig = (id & 7) * 128 + (id >> 3);
  const int r0 = (orig >> 3) * 128;
  const int c0 = (orig & 7) * 128;
  const int t = threadIdx.x;
  const int lane = t & 63, w = t >> 6;
  const int wr = (w >> 1) * 64, wc = (w & 1) * 64;
  const int srow = t >> 3, scol = (t & 7) * 8;
  f32x4 acc[4][4] = {};
  for (int k0 = 0; k0 < kC; k0 += 64) {
#pragma unroll
    for (int it = 0; it < 4; it++) {
      GLOAD16(&xh[(size_t)(r0 + it * 32 + srow) * kC + k0 + scol], &lA[(it * 32 + srow) * 64 + scol]);
      GLOAD16(&Bh[(size_t)(c0 + it * 32 + srow) * kC + k0 + scol], &lB[(it * 32 + srow) * 64 + scol]);
    }
    __syncthreads();
#pragma unroll
    for (int kk = 0; kk < 2; kk++) {
      const int ko = kk * 32 + (lane >> 4) * 8;
      short8 af[4], bfr[4];
#pragma unroll
      for (int i = 0; i < 4; i++)
        af[i] = *reinterpret_cast<const short8*>(&lA[(wr + i * 16 + (lane & 15)) * 64 + ko]);
#pragma unroll
      for (int j = 0; j < 4; j++)
        bfr[j] = *reinterpret_cast<const short8*>(&lB[(wc + j * 16 + (lane & 15)) * 64 + ko]);
#pragma unroll
      for (int i = 0; i < 4; i++)
#pragma unroll
        for (int j = 0; j < 4; j++)
          acc[i][j] = __builtin_amdgcn_mfma_f32_16x16x32_bf16(af[i], bfr[j], acc[i][j], 0, 0, 0);
    }
    __syncthreads();
  }
#pragma unroll
  for (int j = 0; j < 4; j++) {
    const int col = c0 + wc + j * 16 + (lane & 15);
    const float bias = biascat[col];
#pragma unroll
    for (int i = 0; i < 4; i++) {
      const int rbase = r0 + wr + i * 16 + (lane >> 4) * 4;
#pragma unroll
      for (int q = 0; q < 4; q++)
        obuf[(size_t)(rbase + q) * kNC + col] = f2bf(acc[i][j][q] + bias);
    }
  }
}

// ---------- g[r] = dot(xh[r,:], vbq) ----------
__global__ __launch_bounds__(256) void g_kernel(
    const ushort* __restrict__ xh, const float* __restrict__ vbq, float* __restrict__ g) {
  const int wid = threadIdx.x >> 6, lane = threadIdx.x & 63;
  const int r = blockIdx.x * 4 + wid;
  const short8 u = *reinterpret_cast<const short8*>(&xh[(size_t)r * kC + lane * 8]);
  const float4 v0 = *reinterpret_cast<const float4*>(&vbq[lane * 8]);
  const float4 v1 = *reinterpret_cast<const float4*>(&vbq[lane * 8 + 4]);
  float a = bf2f((ushort)u[0]) * v0.x + bf2f((ushort)u[1]) * v0.y +
            bf2f((ushort)u[2]) * v0.z + bf2f((ushort)u[3]) * v0.w +
            bf2f((ushort)u[4]) * v1.x + bf2f((ushort)u[5]) * v1.y +
            bf2f((ushort)u[6]) * v1.z + bf2f((ushort)u[7]) * v1.w;
#pragma unroll
  for (int off = 32; off; off >>= 1) a += __shfl_xor(a, off);
  if (lane == 0) g[r] = a;
}

// ---------- part[b,jc,d] = sum_{j in chunk} cnt[j]*vo[b,j,d] ----------
__global__ __launch_bounds__(256) void svo_part_kernel(
    const ushort* __restrict__ obuf, const int* __restrict__ cnt, float* __restrict__ part) {
  const int d = blockIdx.x * 256 + threadIdx.x;  // 2 blocks
  const int jc = blockIdx.y;                     // 32
  const int b = blockIdx.z;                      // 8
  float a = 0.f;
  for (int j = jc * 64; j < jc * 64 + 64; j++) {
    const int cj = cnt[j];
    if (cj) a += (float)cj * bf2f(obuf[(size_t)(b * kN + j) * kNC + kC + d]);
  }
  part[(size_t)(b * 32 + jc) * kC + d] = a;
}

__global__ __launch_bounds__(256) void svo_reduce_kernel(
    const float* __restrict__ part, float* __restrict__ svo) {
  const int d = blockIdx.x * 256 + threadIdx.x;
  const int b = blockIdx.y;
  float a = 0.f;
#pragma unroll
  for (int jc = 0; jc < 32; jc++) a += part[(size_t)(b * 32 + jc) * kC + d];
  svo[b * kC + d] = a;
}

// ---------- final: s = xh_n . w_j + g_j + bqbk + rb; out = inv*SVO + coef*VO[j2] + bo ----------
__global__ __launch_bounds__(256) void final_kernel(
    const ushort* __restrict__ xh, const ushort* __restrict__ obuf,
    const float* __restrict__ svo, const float* __restrict__ g, const int* __restrict__ nbr,
    const float* __restrict__ bqbk, const float* __restrict__ rb, const float* __restrict__ bo,
    float* __restrict__ out) {
  const int wid = threadIdx.x >> 6, lane = threadIdx.x & 63;
  const int rg = blockIdx.x * 4 + wid;
  const int b = rg >> 11, n = rg & (kN - 1);
  const int j = nbr[n];
  const int j2 = nbr[j];
  const short8 xv = *reinterpret_cast<const short8*>(&xh[(size_t)rg * kC + lane * 8]);
  const short8 wv = *reinterpret_cast<const short8*>(&obuf[(size_t)(b * kN + j) * kNC + lane * 8]);
  float a = 0.f;
#pragma unroll
  for (int q = 0; q < 8; q++) a += bf2f((ushort)xv[q]) * bf2f((ushort)wv[q]);
#pragma unroll
  for (int off = 32; off; off >>= 1) a += __shfl_xor(a, off);
  const float s = a + g[b * kN + j] + bqbk[0] + rb[0];
  const float tt = s * kInvSqrtC;
  const float e = expf(tt);
  const float inv = 1.0f / (e + (float)(kN - 1));
  const float coef = (e - 1.0f) * inv;
  const short8 vv = *reinterpret_cast<const short8*>(&obuf[(size_t)(b * kN + j2) * kNC + kC + lane * 8]);
  const float4 s0 = *reinterpret_cast<const float4*>(&svo[b * kC + lane * 8]);
  const float4 s1 = *reinterpret_cast<const float4*>(&svo[b * kC + lane * 8 + 4]);
  const float4 b0 = *reinterpret_cast<const float4*>(&bo[lane * 8]);
  const float4 b1 = *reinterpret_cast<const float4*>(&bo[lane * 8 + 4]);
  float4 r0, r1;
  r0.x = s0.x * inv + bf2f((ushort)vv[0]) * coef + b0.x;
  r0.y = s0.y * inv + bf2f((ushort)vv[1]) * coef + b0.y;
  r0.z = s0.z * inv + bf2f((ushort)vv[2]) * coef + b0.z;
  r0.w = s0.w * inv + bf2f((ushort)vv[3]) * coef + b0.w;
  r1.x = s1.x * inv + bf2f((ushort)vv[4]) * coef + b1.x;
  r1.y = s1.y * inv + bf2f((ushort)vv[5]) * coef + b1.y;
  r1.z = s1.z * inv + bf2f((ushort)vv[6]) * coef + b1.z;
  r1.w = s1.w * inv + bf2f((ushort)vv[7]) * coef + b1.w;
  *reinterpret_cast<float4*>(&out[(size_t)rg * kC + lane * 8]) = r0;
  *reinterpret_cast<float4*>(&out[(size_t)rg * kC + lane * 8 + 4]) = r1;
}

extern "C" void kernel_launch(void* const* d_in, const int* in_sizes, int n_in,
                              void* d_out, int out_size, void* d_ws, size_t ws_size,
                              hipStream_t stream) {
  const float* x  = (const float*)d_in[0];
  const int* nbr  = (const int*)d_in[1];
  const float* Wq = (const float*)d_in[2];
  const float* bq = (const float*)d_in[3];
  const float* Wk = (const float*)d_in[4];
  const float* bk = (const float*)d_in[5];
  const float* Wv = (const float*)d_in[6];
  const float* bv = (const float*)d_in[7];
  const float* rb = (const float*)d_in[8];
  const float* Wo = (const float*)d_in[9];
  const float* bo = (const float*)d_in[10];
  float* out = (float*)d_out;

  char* ws = (char*)d_ws;
  size_t off = 0;
  auto alloc = [&](size_t bytes) -> void* {
    void* p = ws + off;
    off = (off + bytes + 255) & ~(size_t)255;
    return p;
  };
  ushort* xh    = (ushort*)alloc((size_t)kR * kC * 2);
  ushort* Bh    = (ushort*)alloc((size_t)kNC * kC * 2);
  ushort* obuf  = (ushort*)alloc((size_t)kR * kNC * 2);
  ushort* WqT   = (ushort*)alloc((size_t)kC * kC * 2);
  ushort* WkT   = (ushort*)alloc((size_t)kC * kC * 2);
  ushort* WvT   = (ushort*)alloc((size_t)kC * kC * 2);
  ushort* Woh   = (ushort*)alloc((size_t)kC * kC * 2);
  float* biascat = (float*)alloc(kNC * 4);
  float* vbq    = (float*)alloc(kC * 4);
  float* bqbk   = (float*)alloc(4);
  int*   cnt    = (int*)alloc(kN * 4);
  float* g      = (float*)alloc((size_t)kR * 4);
  float* svo    = (float*)alloc((size_t)kB * kC * 4);
  float* part   = (float*)alloc((size_t)kB * 32 * kC * 4);
  (void)ws_size; (void)n_in; (void)in_sizes; (void)out_size;

  hipMemsetAsync(cnt, 0, kN * sizeof(int), stream);
  cast_kernel<<<kR * kC / (256 * 8), 256, 0, stream>>>(x, xh, nbr, cnt);
  castw_kernel<<<dim3(8, 8, 4), 256, 0, stream>>>(Wq, Wk, Wv, Wo, WqT, WkT, WvT, Woh);
  fold_kernel<<<dim3(8, 8, 2), 256, 0, stream>>>(WqT, WkT, Woh, WvT, Bh);
  biasfold_kernel<<<384, 256, 0, stream>>>(WqT, WkT, Woh, bq, bk, bv, biascat, vbq, bqbk);
  mm_kernel<<<1024, 256, 0, stream>>>(xh, Bh, biascat, obuf);
  g_kernel<<<kR / 4, 256, 0, stream>>>(xh, vbq, g);
  svo_part_kernel<<<dim3(2, 32, kB), 256, 0, stream>>>(obuf, cnt, part);
  svo_reduce_kernel<<<dim3(2, kB), 256, 0, stream>>>(part, svo);
  final_kernel<<<kR / 4, 256, 0, stream>>>(xh, obuf, svo, g, nbr, bqbk, rb, bo, out);
}

// Round 4
// 91.078 us; speedup vs baseline: 4.0571x; 1.0419x over previous
//
#include <hip/hip_runtime.h>
#include <hip/hip_bf16.h>
#include <math.h>

namespace {
constexpr int kB = 8;
constexpr int kN = 2048;
constexpr int kC = 512;
constexpr int kR = kB * kN;          // 16384 rows total
constexpr int kNC = 2 * kC;          // 1024 concatenated output cols
constexpr float kInvSqrtC = 0.044194173824159216f; // 1/sqrt(512)

typedef __attribute__((ext_vector_type(8))) short short8;
typedef __attribute__((ext_vector_type(4))) short short4b;
typedef __attribute__((ext_vector_type(4))) float f32x4;
typedef unsigned short ushort;
}

static __device__ __forceinline__ float bf2f(ushort u) {
  union { unsigned int i; float f; } v; v.i = (unsigned int)u << 16; return v.f;
}
static __device__ __forceinline__ ushort f2bf(float f) {
  __hip_bfloat16 h = __float2bfloat16(f);
  union { __hip_bfloat16 h; ushort u; } cv; cv.h = h; return cv.u;
}

#define GLOAD16(G, L) __builtin_amdgcn_global_load_lds( \
    (const __attribute__((address_space(1))) unsigned int*)(G), \
    (__attribute__((address_space(3))) unsigned int*)(L), 16, 0, 0)

// ---------- neighbor-count histogram, one block, LDS atomics (no global memset) ----------
__global__ __launch_bounds__(1024) void hist_kernel(
    const int* __restrict__ nbr, int* __restrict__ cnt) {
  __shared__ int h[kN];
  const int t = threadIdx.x;
  h[t] = 0; h[t + 1024] = 0;
  __syncthreads();
  atomicAdd(&h[nbr[t]], 1);
  atomicAdd(&h[nbr[t + 1024]], 1);
  __syncthreads();
  cnt[t] = h[t];
  cnt[t + 1024] = h[t + 1024];
}

// ---------- weights fp32 -> bf16 (3 transposed + 1 straight) ----------
// z=0: WqT[c][d]=Wq[d][c]; z=1: WkT[e][d]=Wk[d][e]; z=2: WvT[e][c]=Wv[c][e]; z=3: Woh=Wo
__global__ __launch_bounds__(256) void castw_kernel(
    const float* __restrict__ Wq, const float* __restrict__ Wk,
    const float* __restrict__ Wv, const float* __restrict__ Wo,
    ushort* __restrict__ WqT, ushort* __restrict__ WkT,
    ushort* __restrict__ WvT, ushort* __restrict__ Woh) {
  const int z = blockIdx.z;
  const int d0 = blockIdx.x * 64, c0 = blockIdx.y * 64;
  const int t = threadIdx.x;
  if (z == 3) {
#pragma unroll
    for (int i = 0; i < 4; i++) {
      const int row = i * 16 + (t >> 4), col4 = (t & 15) * 4;
      const float4 v = *reinterpret_cast<const float4*>(&Wo[(d0 + row) * kC + c0 + col4]);
      short4b o;
      o[0] = (short)f2bf(v.x); o[1] = (short)f2bf(v.y);
      o[2] = (short)f2bf(v.z); o[3] = (short)f2bf(v.w);
      *reinterpret_cast<short4b*>(&Woh[(d0 + row) * kC + c0 + col4]) = o;
    }
    return;
  }
  __shared__ float ld[64][65];
  const float* S = (z == 0) ? Wq : ((z == 1) ? Wk : Wv);
  ushort* T = (z == 0) ? WqT : ((z == 1) ? WkT : WvT);
#pragma unroll
  for (int i = 0; i < 4; i++) {
    const int dl = i * 16 + (t >> 4), cl4 = (t & 15) * 4;
    const float4 v = *reinterpret_cast<const float4*>(&S[(d0 + dl) * kC + c0 + cl4]);
    ld[dl][cl4 + 0] = v.x; ld[dl][cl4 + 1] = v.y;
    ld[dl][cl4 + 2] = v.z; ld[dl][cl4 + 3] = v.w;
  }
  __syncthreads();
#pragma unroll
  for (int i = 0; i < 4; i++) {
    const int cl = i * 16 + (t >> 4), dl4 = (t & 15) * 4;
    short4b o;
#pragma unroll
    for (int q = 0; q < 4; q++) o[q] = (short)f2bf(ld[dl4 + q][cl]);
    *reinterpret_cast<short4b*>(&T[(size_t)(c0 + cl) * kC + d0 + dl4]) = o;
  }
}

// ---------- MFMA fold: z=0 -> Bh[0:512) = A = WqT @ WkT^T ; z=1 -> Bh[512:1024) = M = Wo @ WvT^T ----------
__global__ __launch_bounds__(256) void fold_kernel(
    const ushort* __restrict__ WqT, const ushort* __restrict__ WkT,
    const ushort* __restrict__ Woh, const ushort* __restrict__ WvT,
    ushort* __restrict__ Bh) {
  __shared__ ushort lA[64 * 64];
  __shared__ ushort lB[64 * 64];
  const int z = blockIdx.z;
  const ushort* Ap = z ? Woh : WqT;
  const ushort* Bp = z ? WvT : WkT;
  const int r0 = blockIdx.y * 64, c0 = blockIdx.x * 64;
  const int t = threadIdx.x, lane = t & 63, w = t >> 6;
  const int wr = (w >> 1) * 32, wc = (w & 1) * 32;
  const int srow = t >> 3, scol = (t & 7) * 8;
  f32x4 acc[2][2] = {};
  for (int k0 = 0; k0 < kC; k0 += 64) {
#pragma unroll
    for (int it = 0; it < 2; it++) {
      GLOAD16(&Ap[(size_t)(r0 + it * 32 + srow) * kC + k0 + scol], &lA[(it * 32 + srow) * 64 + scol]);
      GLOAD16(&Bp[(size_t)(c0 + it * 32 + srow) * kC + k0 + scol], &lB[(it * 32 + srow) * 64 + scol]);
    }
    __syncthreads();
#pragma unroll
    for (int kk = 0; kk < 2; kk++) {
      const int ko = kk * 32 + (lane >> 4) * 8;
      short8 af[2], bfr[2];
#pragma unroll
      for (int i = 0; i < 2; i++)
        af[i] = *reinterpret_cast<const short8*>(&lA[(wr + i * 16 + (lane & 15)) * 64 + ko]);
#pragma unroll
      for (int j = 0; j < 2; j++)
        bfr[j] = *reinterpret_cast<const short8*>(&lB[(wc + j * 16 + (lane & 15)) * 64 + ko]);
#pragma unroll
      for (int i = 0; i < 2; i++)
#pragma unroll
        for (int j = 0; j < 2; j++)
          acc[i][j] = __builtin_amdgcn_mfma_f32_16x16x32_bf16(af[i], bfr[j], acc[i][j], 0, 0, 0);
    }
    __syncthreads();
  }
#pragma unroll
  for (int j = 0; j < 2; j++) {
    const int col = c0 + wc + j * 16 + (lane & 15);
#pragma unroll
    for (int i = 0; i < 2; i++) {
      const int rbase = r0 + wr + i * 16 + (lane >> 4) * 4;
#pragma unroll
      for (int q = 0; q < 4; q++)
        Bh[(size_t)(z * kC + rbase + q) * kC + col] = f2bf(acc[i][j][q]);
    }
  }
}

// ---------- bias folds: wave-per-row bf16 dots ----------
// gid<512: biascat[c]=WqT[c,:].bk ; 512<=gid<1024: vbq[e]=WkT[e,:].bq ; else biascat[512+d]=Woh[d,:].bv
__global__ __launch_bounds__(256) void biasfold_kernel(
    const ushort* __restrict__ WqT, const ushort* __restrict__ WkT, const ushort* __restrict__ Woh,
    const float* __restrict__ bq, const float* __restrict__ bk, const float* __restrict__ bv,
    float* __restrict__ biascat, float* __restrict__ vbq, float* __restrict__ bqbk) {
  const int wid = threadIdx.x >> 6, lane = threadIdx.x & 63;
  const int gid = blockIdx.x * 4 + wid;  // 0..1535
  const ushort* rowp;
  const float* vec;
  if (gid < 512)       { rowp = &WqT[(size_t)gid * kC];          vec = bk; }
  else if (gid < 1024) { rowp = &WkT[(size_t)(gid - 512) * kC];  vec = bq; }
  else                 { rowp = &Woh[(size_t)(gid - 1024) * kC]; vec = bv; }
  const short8 u = *reinterpret_cast<const short8*>(&rowp[lane * 8]);
  const float4 v0 = *reinterpret_cast<const float4*>(&vec[lane * 8]);
  const float4 v1 = *reinterpret_cast<const float4*>(&vec[lane * 8 + 4]);
  float a = bf2f((ushort)u[0]) * v0.x + bf2f((ushort)u[1]) * v0.y +
            bf2f((ushort)u[2]) * v0.z + bf2f((ushort)u[3]) * v0.w +
            bf2f((ushort)u[4]) * v1.x + bf2f((ushort)u[5]) * v1.y +
            bf2f((ushort)u[6]) * v1.z + bf2f((ushort)u[7]) * v1.w;
#pragma unroll
  for (int off = 32; off; off >>= 1) a += __shfl_xor(a, off);
  if (lane == 0) {
    if (gid < 512) biascat[gid] = a;
    else if (gid < 1024) vbq[gid - 512] = a;
    else biascat[gid - 512] = a;
  }
  if (blockIdx.x == 0 && wid == 1) {
    const float4 q0 = *reinterpret_cast<const float4*>(&bq[lane * 8]);
    const float4 q1 = *reinterpret_cast<const float4*>(&bq[lane * 8 + 4]);
    const float4 k0 = *reinterpret_cast<const float4*>(&bk[lane * 8]);
    const float4 k1 = *reinterpret_cast<const float4*>(&bk[lane * 8 + 4]);
    float s = q0.x * k0.x + q0.y * k0.y + q0.z * k0.z + q0.w * k0.w +
              q1.x * k1.x + q1.y * k1.y + q1.z * k1.z + q1.w * k1.w;
#pragma unroll
    for (int off = 32; off; off >>= 1) s += __shfl_xor(s, off);
    if (lane == 0) bqbk[0] = s;
  }
}

// ---------- fused: x (fp32) -> xh (bf16) AND g[r] = dot(x[r,:], vbq) ----------
__global__ __launch_bounds__(256) void castg_kernel(
    const float* __restrict__ x, const float* __restrict__ vbq,
    ushort* __restrict__ xh, float* __restrict__ g) {
  const int wid = threadIdx.x >> 6, lane = threadIdx.x & 63;
  const int r = blockIdx.x * 4 + wid;
  const float4 a = *reinterpret_cast<const float4*>(&x[(size_t)r * kC + lane * 8]);
  const float4 b = *reinterpret_cast<const float4*>(&x[(size_t)r * kC + lane * 8 + 4]);
  short8 o;
  o[0] = (short)f2bf(a.x); o[1] = (short)f2bf(a.y);
  o[2] = (short)f2bf(a.z); o[3] = (short)f2bf(a.w);
  o[4] = (short)f2bf(b.x); o[5] = (short)f2bf(b.y);
  o[6] = (short)f2bf(b.z); o[7] = (short)f2bf(b.w);
  *reinterpret_cast<short8*>(&xh[(size_t)r * kC + lane * 8]) = o;
  const float4 v0 = *reinterpret_cast<const float4*>(&vbq[lane * 8]);
  const float4 v1 = *reinterpret_cast<const float4*>(&vbq[lane * 8 + 4]);
  float acc = a.x * v0.x + a.y * v0.y + a.z * v0.z + a.w * v0.w +
              b.x * v1.x + b.y * v1.y + b.z * v1.z + b.w * v1.w;
#pragma unroll
  for (int off = 32; off; off >>= 1) acc += __shfl_xor(acc, off);
  if (lane == 0) g[r] = acc;
}

// ---------- big fused GEMM: obuf[r, 0:512] = w = xh@A^T (+ubk),
// ----------                 obuf[r, 512:1024] = vo = xh@M^T (+bvo) ----------
__global__ __launch_bounds__(256) void mm_kernel(
    const ushort* __restrict__ xh, const ushort* __restrict__ Bh,
    const float* __restrict__ biascat, ushort* __restrict__ obuf) {
  __shared__ ushort lA[128 * 64];
  __shared__ ushort lB[128 * 64];
  const int id = blockIdx.x;
  const int orig = (id & 7) * 128 + (id >> 3);
  const int r0 = (orig >> 3) * 128;
  const int c0 = (orig & 7) * 128;
  const int t = threadIdx.x;
  const int lane = t & 63, w = t >> 6;
  const int wr = (w >> 1) * 64, wc = (w & 1) * 64;
  const int srow = t >> 3, scol = (t & 7) * 8;
  f32x4 acc[4][4] = {};
  for (int k0 = 0; k0 < kC; k0 += 64) {
#pragma unroll
    for (int it = 0; it < 4; it++) {
      GLOAD16(&xh[(size_t)(r0 + it * 32 + srow) * kC + k0 + scol], &lA[(it * 32 + srow) * 64 + scol]);
      GLOAD16(&Bh[(size_t)(c0 + it * 32 + srow) * kC + k0 + scol], &lB[(it * 32 + srow) * 64 + scol]);
    }
    __syncthreads();
#pragma unroll
    for (int kk = 0; kk < 2; kk++) {
      const int ko = kk * 32 + (lane >> 4) * 8;
      short8 af[4], bfr[4];
#pragma unroll
      for (int i = 0; i < 4; i++)
        af[i] = *reinterpret_cast<const short8*>(&lA[(wr + i * 16 + (lane & 15)) * 64 + ko]);
#pragma unroll
      for (int j = 0; j < 4; j++)
        bfr[j] = *reinterpret_cast<const short8*>(&lB[(wc + j * 16 + (lane & 15)) * 64 + ko]);
#pragma unroll
      for (int i = 0; i < 4; i++)
#pragma unroll
        for (int j = 0; j < 4; j++)
          acc[i][j] = __builtin_amdgcn_mfma_f32_16x16x32_bf16(af[i], bfr[j], acc[i][j], 0, 0, 0);
    }
    __syncthreads();
  }
#pragma unroll
  for (int j = 0; j < 4; j++) {
    const int col = c0 + wc + j * 16 + (lane & 15);
    const float bias = biascat[col];
#pragma unroll
    for (int i = 0; i < 4; i++) {
      const int rbase = r0 + wr + i * 16 + (lane >> 4) * 4;
#pragma unroll
      for (int q = 0; q < 4; q++)
        obuf[(size_t)(rbase + q) * kNC + col] = f2bf(acc[i][j][q] + bias);
    }
  }
}

// ---------- part[b,jc,d] = sum_{j in chunk} cnt[j]*vo[b,j,d] ----------
__global__ __launch_bounds__(256) void svo_part_kernel(
    const ushort* __restrict__ obuf, const int* __restrict__ cnt, float* __restrict__ part) {
  const int d = blockIdx.x * 256 + threadIdx.x;  // 2 blocks
  const int jc = blockIdx.y;                     // 32
  const int b = blockIdx.z;                      // 8
  float a = 0.f;
  for (int j = jc * 64; j < jc * 64 + 64; j++) {
    const int cj = cnt[j];
    if (cj) a += (float)cj * bf2f(obuf[(size_t)(b * kN + j) * kNC + kC + d]);
  }
  part[(size_t)(b * 32 + jc) * kC + d] = a;
}

__global__ __launch_bounds__(256) void svo_reduce_kernel(
    const float* __restrict__ part, float* __restrict__ svo) {
  const int d = blockIdx.x * 256 + threadIdx.x;
  const int b = blockIdx.y;
  float a = 0.f;
#pragma unroll
  for (int jc = 0; jc < 32; jc++) a += part[(size_t)(b * 32 + jc) * kC + d];
  svo[b * kC + d] = a;
}

// ---------- final: s = xh_n . w_j + g_j + bqbk + rb; out = inv*SVO + coef*VO[j2] + bo ----------
__global__ __launch_bounds__(256) void final_kernel(
    const ushort* __restrict__ xh, const ushort* __restrict__ obuf,
    const float* __restrict__ svo, const float* __restrict__ g, const int* __restrict__ nbr,
    const float* __restrict__ bqbk, const float* __restrict__ rb, const float* __restrict__ bo,
    float* __restrict__ out) {
  const int wid = threadIdx.x >> 6, lane = threadIdx.x & 63;
  const int rg = blockIdx.x * 4 + wid;
  const int b = rg >> 11, n = rg & (kN - 1);
  const int j = nbr[n];
  const int j2 = nbr[j];
  const short8 xv = *reinterpret_cast<const short8*>(&xh[(size_t)rg * kC + lane * 8]);
  const short8 wv = *reinterpret_cast<const short8*>(&obuf[(size_t)(b * kN + j) * kNC + lane * 8]);
  float a = 0.f;
#pragma unroll
  for (int q = 0; q < 8; q++) a += bf2f((ushort)xv[q]) * bf2f((ushort)wv[q]);
#pragma unroll
  for (int off = 32; off; off >>= 1) a += __shfl_xor(a, off);
  const float s = a + g[b * kN + j] + bqbk[0] + rb[0];
  const float tt = s * kInvSqrtC;
  const float e = expf(tt);
  const float inv = 1.0f / (e + (float)(kN - 1));
  const float coef = (e - 1.0f) * inv;
  const short8 vv = *reinterpret_cast<const short8*>(&obuf[(size_t)(b * kN + j2) * kNC + kC + lane * 8]);
  const float4 s0 = *reinterpret_cast<const float4*>(&svo[b * kC + lane * 8]);
  const float4 s1 = *reinterpret_cast<const float4*>(&svo[b * kC + lane * 8 + 4]);
  const float4 b0 = *reinterpret_cast<const float4*>(&bo[lane * 8]);
  const float4 b1 = *reinterpret_cast<const float4*>(&bo[lane * 8 + 4]);
  float4 r0, r1;
  r0.x = s0.x * inv + bf2f((ushort)vv[0]) * coef + b0.x;
  r0.y = s0.y * inv + bf2f((ushort)vv[1]) * coef + b0.y;
  r0.z = s0.z * inv + bf2f((ushort)vv[2]) * coef + b0.z;
  r0.w = s0.w * inv + bf2f((ushort)vv[3]) * coef + b0.w;
  r1.x = s1.x * inv + bf2f((ushort)vv[4]) * coef + b1.x;
  r1.y = s1.y * inv + bf2f((ushort)vv[5]) * coef + b1.y;
  r1.z = s1.z * inv + bf2f((ushort)vv[6]) * coef + b1.z;
  r1.w = s1.w * inv + bf2f((ushort)vv[7]) * coef + b1.w;
  *reinterpret_cast<float4*>(&out[(size_t)rg * kC + lane * 8]) = r0;
  *reinterpret_cast<float4*>(&out[(size_t)rg * kC + lane * 8 + 4]) = r1;
}

extern "C" void kernel_launch(void* const* d_in, const int* in_sizes, int n_in,
                              void* d_out, int out_size, void* d_ws, size_t ws_size,
                              hipStream_t stream) {
  const float* x  = (const float*)d_in[0];
  const int* nbr  = (const int*)d_in[1];
  const float* Wq = (const float*)d_in[2];
  const float* bq = (const float*)d_in[3];
  const float* Wk = (const float*)d_in[4];
  const float* bk = (const float*)d_in[5];
  const float* Wv = (const float*)d_in[6];
  const float* bv = (const float*)d_in[7];
  const float* rb = (const float*)d_in[8];
  const float* Wo = (const float*)d_in[9];
  const float* bo = (const float*)d_in[10];
  float* out = (float*)d_out;

  char* ws = (char*)d_ws;
  size_t off = 0;
  auto alloc = [&](size_t bytes) -> void* {
    void* p = ws + off;
    off = (off + bytes + 255) & ~(size_t)255;
    return p;
  };
  ushort* xh    = (ushort*)alloc((size_t)kR * kC * 2);
  ushort* Bh    = (ushort*)alloc((size_t)kNC * kC * 2);
  ushort* obuf  = (ushort*)alloc((size_t)kR * kNC * 2);
  ushort* WqT   = (ushort*)alloc((size_t)kC * kC * 2);
  ushort* WkT   = (ushort*)alloc((size_t)kC * kC * 2);
  ushort* WvT   = (ushort*)alloc((size_t)kC * kC * 2);
  ushort* Woh   = (ushort*)alloc((size_t)kC * kC * 2);
  float* biascat = (float*)alloc(kNC * 4);
  float* vbq    = (float*)alloc(kC * 4);
  float* bqbk   = (float*)alloc(4);
  int*   cnt    = (int*)alloc(kN * 4);
  float* g      = (float*)alloc((size_t)kR * 4);
  float* svo    = (float*)alloc((size_t)kB * kC * 4);
  float* part   = (float*)alloc((size_t)kB * 32 * kC * 4);
  (void)ws_size; (void)n_in; (void)in_sizes; (void)out_size;

  hist_kernel<<<1, 1024, 0, stream>>>(nbr, cnt);
  castw_kernel<<<dim3(8, 8, 4), 256, 0, stream>>>(Wq, Wk, Wv, Wo, WqT, WkT, WvT, Woh);
  fold_kernel<<<dim3(8, 8, 2), 256, 0, stream>>>(WqT, WkT, Woh, WvT, Bh);
  biasfold_kernel<<<384, 256, 0, stream>>>(WqT, WkT, Woh, bq, bk, bv, biascat, vbq, bqbk);
  castg_kernel<<<kR / 4, 256, 0, stream>>>(x, vbq, xh, g);
  mm_kernel<<<1024, 256, 0, stream>>>(xh, Bh, biascat, obuf);
  svo_part_kernel<<<dim3(2, 32, kB), 256, 0, stream>>>(obuf, cnt, part);
  svo_reduce_kernel<<<dim3(2, kB), 256, 0, stream>>>(part, svo);
  final_kernel<<<kR / 4, 256, 0, stream>>>(xh, obuf, svo, g, nbr, bqbk, rb, bo, out);
}

// Round 5
// 84.658 us; speedup vs baseline: 4.3648x; 1.0758x over previous
//
#include <hip/hip_runtime.h>
#include <hip/hip_bf16.h>
#include <math.h>

namespace {
constexpr int kB = 8;
constexpr int kN = 2048;
constexpr int kC = 512;
constexpr int kR = kB * kN;          // 16384 rows total
constexpr int kNC = 2 * kC;          // 1024 concatenated output cols
constexpr float kInvSqrtC = 0.044194173824159216f; // 1/sqrt(512)

typedef __attribute__((ext_vector_type(8))) short short8;
typedef __attribute__((ext_vector_type(4))) short short4b;
typedef __attribute__((ext_vector_type(4))) float f32x4;
typedef unsigned short ushort;
}

static __device__ __forceinline__ float bf2f(ushort u) {
  union { unsigned int i; float f; } v; v.i = (unsigned int)u << 16; return v.f;
}
static __device__ __forceinline__ ushort f2bf(float f) {
  __hip_bfloat16 h = __float2bfloat16(f);
  union { __hip_bfloat16 h; ushort u; } cv; cv.h = h; return cv.u;
}

#define GLOAD16(G, L) __builtin_amdgcn_global_load_lds( \
    (const __attribute__((address_space(1))) unsigned int*)(G), \
    (__attribute__((address_space(3))) unsigned int*)(L), 16, 0, 0)

// ---------- weights fp32 -> bf16 (3 transposed + 1 straight) + neighbor histogram ----------
// z=0: WqT[c][d]=Wq[d][c]; z=1: WkT[e][d]=Wk[d][e]; z=2: WvT[e][c]=Wv[c][e]; z=3: Woh=Wo; z=4: hist
__global__ __launch_bounds__(256) void castw_kernel(
    const float* __restrict__ Wq, const float* __restrict__ Wk,
    const float* __restrict__ Wv, const float* __restrict__ Wo,
    ushort* __restrict__ WqT, ushort* __restrict__ WkT,
    ushort* __restrict__ WvT, ushort* __restrict__ Woh,
    const int* __restrict__ nbr, int* __restrict__ cnt) {
  const int z = blockIdx.z;
  const int t = threadIdx.x;
  if (z == 4) {
    if (blockIdx.x || blockIdx.y) return;
    __shared__ int h[kN];
#pragma unroll
    for (int i = 0; i < 8; i++) h[t + i * 256] = 0;
    __syncthreads();
#pragma unroll
    for (int i = 0; i < 8; i++) atomicAdd(&h[nbr[t + i * 256]], 1);
    __syncthreads();
#pragma unroll
    for (int i = 0; i < 8; i++) cnt[t + i * 256] = h[t + i * 256];
    return;
  }
  const int d0 = blockIdx.x * 64, c0 = blockIdx.y * 64;
  if (z == 3) {
#pragma unroll
    for (int i = 0; i < 4; i++) {
      const int row = i * 16 + (t >> 4), col4 = (t & 15) * 4;
      const float4 v = *reinterpret_cast<const float4*>(&Wo[(d0 + row) * kC + c0 + col4]);
      short4b o;
      o[0] = (short)f2bf(v.x); o[1] = (short)f2bf(v.y);
      o[2] = (short)f2bf(v.z); o[3] = (short)f2bf(v.w);
      *reinterpret_cast<short4b*>(&Woh[(d0 + row) * kC + c0 + col4]) = o;
    }
    return;
  }
  __shared__ float ld[64][65];
  const float* S = (z == 0) ? Wq : ((z == 1) ? Wk : Wv);
  ushort* T = (z == 0) ? WqT : ((z == 1) ? WkT : WvT);
#pragma unroll
  for (int i = 0; i < 4; i++) {
    const int dl = i * 16 + (t >> 4), cl4 = (t & 15) * 4;
    const float4 v = *reinterpret_cast<const float4*>(&S[(d0 + dl) * kC + c0 + cl4]);
    ld[dl][cl4 + 0] = v.x; ld[dl][cl4 + 1] = v.y;
    ld[dl][cl4 + 2] = v.z; ld[dl][cl4 + 3] = v.w;
  }
  __syncthreads();
#pragma unroll
  for (int i = 0; i < 4; i++) {
    const int cl = i * 16 + (t >> 4), dl4 = (t & 15) * 4;
    short4b o;
#pragma unroll
    for (int q = 0; q < 4; q++) o[q] = (short)f2bf(ld[dl4 + q][cl]);
    *reinterpret_cast<short4b*>(&T[(size_t)(c0 + cl) * kC + d0 + dl4]) = o;
  }
}

// ---------- MFMA fold + bias folds ----------
// z=0 -> Bh[0:512) = A = WqT @ WkT^T ; z=1 -> Bh[512:1024) = Wo @ WvT^T ; z=2 -> bias dots
__global__ __launch_bounds__(256) void fold_kernel(
    const ushort* __restrict__ WqT, const ushort* __restrict__ WkT,
    const ushort* __restrict__ Woh, const ushort* __restrict__ WvT,
    ushort* __restrict__ Bh,
    const float* __restrict__ bq, const float* __restrict__ bk, const float* __restrict__ bv,
    float* __restrict__ biascat, float* __restrict__ vbq, float* __restrict__ bqbk) {
  const int t = threadIdx.x, lane = t & 63, w = t >> 6;
  const int z = blockIdx.z;
  if (z == 2) {
    const int fid = blockIdx.y * 8 + blockIdx.x;     // 0..63
    const int gw = fid * 4 + w;                      // 0..255
    for (int rr = gw; rr < 1536; rr += 256) {
      const ushort* rowp; const float* vec;
      if (rr < 512)       { rowp = &WqT[(size_t)rr * kC];          vec = bk; }
      else if (rr < 1024) { rowp = &WkT[(size_t)(rr - 512) * kC];  vec = bq; }
      else                { rowp = &Woh[(size_t)(rr - 1024) * kC]; vec = bv; }
      const short8 u = *reinterpret_cast<const short8*>(&rowp[lane * 8]);
      const float4 v0 = *reinterpret_cast<const float4*>(&vec[lane * 8]);
      const float4 v1 = *reinterpret_cast<const float4*>(&vec[lane * 8 + 4]);
      float a = bf2f((ushort)u[0]) * v0.x + bf2f((ushort)u[1]) * v0.y +
                bf2f((ushort)u[2]) * v0.z + bf2f((ushort)u[3]) * v0.w +
                bf2f((ushort)u[4]) * v1.x + bf2f((ushort)u[5]) * v1.y +
                bf2f((ushort)u[6]) * v1.z + bf2f((ushort)u[7]) * v1.w;
#pragma unroll
      for (int off = 32; off; off >>= 1) a += __shfl_xor(a, off);
      if (lane == 0) {
        if (rr < 512) biascat[rr] = a;
        else if (rr < 1024) vbq[rr - 512] = a;
        else biascat[rr - 512] = a;
      }
    }
    if (gw == 0) {
      const float4 q0 = *reinterpret_cast<const float4*>(&bq[lane * 8]);
      const float4 q1 = *reinterpret_cast<const float4*>(&bq[lane * 8 + 4]);
      const float4 k0 = *reinterpret_cast<const float4*>(&bk[lane * 8]);
      const float4 k1 = *reinterpret_cast<const float4*>(&bk[lane * 8 + 4]);
      float s = q0.x * k0.x + q0.y * k0.y + q0.z * k0.z + q0.w * k0.w +
                q1.x * k1.x + q1.y * k1.y + q1.z * k1.z + q1.w * k1.w;
#pragma unroll
      for (int off = 32; off; off >>= 1) s += __shfl_xor(s, off);
      if (lane == 0) bqbk[0] = s;
    }
    return;
  }
  __shared__ ushort lA[64 * 64];
  __shared__ ushort lB[64 * 64];
  const ushort* Ap = z ? Woh : WqT;
  const ushort* Bp = z ? WvT : WkT;
  const int r0 = blockIdx.y * 64, c0 = blockIdx.x * 64;
  const int wr = (w >> 1) * 32, wc = (w & 1) * 32;
  const int srow = t >> 3, scol = (t & 7) * 8;
  f32x4 acc[2][2] = {};
  for (int k0 = 0; k0 < kC; k0 += 64) {
#pragma unroll
    for (int it = 0; it < 2; it++) {
      GLOAD16(&Ap[(size_t)(r0 + it * 32 + srow) * kC + k0 + scol], &lA[(it * 32 + srow) * 64 + scol]);
      GLOAD16(&Bp[(size_t)(c0 + it * 32 + srow) * kC + k0 + scol], &lB[(it * 32 + srow) * 64 + scol]);
    }
    __syncthreads();
#pragma unroll
    for (int kk = 0; kk < 2; kk++) {
      const int ko = kk * 32 + (lane >> 4) * 8;
      short8 af[2], bfr[2];
#pragma unroll
      for (int i = 0; i < 2; i++)
        af[i] = *reinterpret_cast<const short8*>(&lA[(wr + i * 16 + (lane & 15)) * 64 + ko]);
#pragma unroll
      for (int j = 0; j < 2; j++)
        bfr[j] = *reinterpret_cast<const short8*>(&lB[(wc + j * 16 + (lane & 15)) * 64 + ko]);
#pragma unroll
      for (int i = 0; i < 2; i++)
#pragma unroll
        for (int j = 0; j < 2; j++)
          acc[i][j] = __builtin_amdgcn_mfma_f32_16x16x32_bf16(af[i], bfr[j], acc[i][j], 0, 0, 0);
    }
    __syncthreads();
  }
#pragma unroll
  for (int j = 0; j < 2; j++) {
    const int col = c0 + wc + j * 16 + (lane & 15);
#pragma unroll
    for (int i = 0; i < 2; i++) {
      const int rbase = r0 + wr + i * 16 + (lane >> 4) * 4;
#pragma unroll
      for (int q = 0; q < 4; q++)
        Bh[(size_t)(z * kC + rbase + q) * kC + col] = f2bf(acc[i][j][q]);
    }
  }
}

// ---------- fused: x (fp32) -> xh (bf16) AND g[r] = dot(x[r,:], vbq) ----------
__global__ __launch_bounds__(256) void castg_kernel(
    const float* __restrict__ x, const float* __restrict__ vbq,
    ushort* __restrict__ xh, float* __restrict__ g) {
  const int wid = threadIdx.x >> 6, lane = threadIdx.x & 63;
  const int r = blockIdx.x * 4 + wid;
  const float4 a = *reinterpret_cast<const float4*>(&x[(size_t)r * kC + lane * 8]);
  const float4 b = *reinterpret_cast<const float4*>(&x[(size_t)r * kC + lane * 8 + 4]);
  short8 o;
  o[0] = (short)f2bf(a.x); o[1] = (short)f2bf(a.y);
  o[2] = (short)f2bf(a.z); o[3] = (short)f2bf(a.w);
  o[4] = (short)f2bf(b.x); o[5] = (short)f2bf(b.y);
  o[6] = (short)f2bf(b.z); o[7] = (short)f2bf(b.w);
  *reinterpret_cast<short8*>(&xh[(size_t)r * kC + lane * 8]) = o;
  const float4 v0 = *reinterpret_cast<const float4*>(&vbq[lane * 8]);
  const float4 v1 = *reinterpret_cast<const float4*>(&vbq[lane * 8 + 4]);
  float acc = a.x * v0.x + a.y * v0.y + a.z * v0.z + a.w * v0.w +
              b.x * v1.x + b.y * v1.y + b.z * v1.z + b.w * v1.w;
#pragma unroll
  for (int off = 32; off; off >>= 1) acc += __shfl_xor(acc, off);
  if (lane == 0) g[r] = acc;
}

// ---------- big fused GEMM, double-buffered (T3 minimal): ----------
// obuf[r,0:512]=w=xh@A^T (+ubk); obuf[r,512:1024]=vo=xh@M^T (+bvo)
__global__ __launch_bounds__(256) void mm_kernel(
    const ushort* __restrict__ xh, const ushort* __restrict__ Bh,
    const float* __restrict__ biascat, ushort* __restrict__ obuf) {
  __shared__ ushort lA[2][128 * 64];
  __shared__ ushort lB[2][128 * 64];
  const int id = blockIdx.x;
  const int orig = (id & 7) * 128 + (id >> 3);   // XCD-aware swizzle (1024 % 8 == 0)
  const int r0 = (orig >> 3) * 128;
  const int c0 = (orig & 7) * 128;
  const int t = threadIdx.x;
  const int lane = t & 63, w = t >> 6;
  const int wr = (w >> 1) * 64, wc = (w & 1) * 64;
  const int srow = t >> 3, scol = (t & 7) * 8;
  f32x4 acc[4][4] = {};

  auto stage = [&](int buf, int k0) {
#pragma unroll
    for (int it = 0; it < 4; it++) {
      GLOAD16(&xh[(size_t)(r0 + it * 32 + srow) * kC + k0 + scol],
              &lA[buf][(it * 32 + srow) * 64 + scol]);
      GLOAD16(&Bh[(size_t)(c0 + it * 32 + srow) * kC + k0 + scol],
              &lB[buf][(it * 32 + srow) * 64 + scol]);
    }
  };

  stage(0, 0);
  __syncthreads();                       // drains vmcnt(0): buf0 ready
  int cur = 0;
#pragma unroll
  for (int ts = 0; ts < 8; ++ts) {
    if (ts < 7) stage(cur ^ 1, (ts + 1) * 64);   // issue next tile, in flight under MFMA
#pragma unroll
    for (int kk = 0; kk < 2; kk++) {
      const int ko = kk * 32 + (lane >> 4) * 8;
      short8 af[4], bfr[4];
#pragma unroll
      for (int i = 0; i < 4; i++)
        af[i] = *reinterpret_cast<const short8*>(&lA[cur][(wr + i * 16 + (lane & 15)) * 64 + ko]);
#pragma unroll
      for (int j = 0; j < 4; j++)
        bfr[j] = *reinterpret_cast<const short8*>(&lB[cur][(wc + j * 16 + (lane & 15)) * 64 + ko]);
      __builtin_amdgcn_s_setprio(1);
#pragma unroll
      for (int i = 0; i < 4; i++)
#pragma unroll
        for (int j = 0; j < 4; j++)
          acc[i][j] = __builtin_amdgcn_mfma_f32_16x16x32_bf16(af[i], bfr[j], acc[i][j], 0, 0, 0);
      __builtin_amdgcn_s_setprio(0);
    }
    __syncthreads();                     // one barrier per K-step; drains prefetch
    cur ^= 1;
  }
#pragma unroll
  for (int j = 0; j < 4; j++) {
    const int col = c0 + wc + j * 16 + (lane & 15);
    const float bias = biascat[col];
#pragma unroll
    for (int i = 0; i < 4; i++) {
      const int rbase = r0 + wr + i * 16 + (lane >> 4) * 4;
#pragma unroll
      for (int q = 0; q < 4; q++)
        obuf[(size_t)(rbase + q) * kNC + col] = f2bf(acc[i][j][q] + bias);
    }
  }
}

// ---------- part[b,jc,d] = sum_{j in chunk} cnt[j]*vo[b,j,d] ----------
__global__ __launch_bounds__(256) void svo_part_kernel(
    const ushort* __restrict__ obuf, const int* __restrict__ cnt, float* __restrict__ part) {
  const int d = blockIdx.x * 256 + threadIdx.x;  // 2 blocks
  const int jc = blockIdx.y;                     // 32
  const int b = blockIdx.z;                      // 8
  float a = 0.f;
  for (int j = jc * 64; j < jc * 64 + 64; j++) {
    const int cj = cnt[j];
    if (cj) a += (float)cj * bf2f(obuf[(size_t)(b * kN + j) * kNC + kC + d]);
  }
  part[(size_t)(b * 32 + jc) * kC + d] = a;
}

__global__ __launch_bounds__(256) void svo_reduce_kernel(
    const float* __restrict__ part, float* __restrict__ svo) {
  const int d = blockIdx.x * 256 + threadIdx.x;
  const int b = blockIdx.y;
  float a = 0.f;
#pragma unroll
  for (int jc = 0; jc < 32; jc++) a += part[(size_t)(b * 32 + jc) * kC + d];
  svo[b * kC + d] = a;
}

// ---------- final: s = xh_n . w_j + g_j + bqbk + rb; out = inv*SVO + coef*VO[j2] + bo ----------
__global__ __launch_bounds__(256) void final_kernel(
    const ushort* __restrict__ xh, const ushort* __restrict__ obuf,
    const float* __restrict__ svo, const float* __restrict__ g, const int* __restrict__ nbr,
    const float* __restrict__ bqbk, const float* __restrict__ rb, const float* __restrict__ bo,
    float* __restrict__ out) {
  const int wid = threadIdx.x >> 6, lane = threadIdx.x & 63;
  const int rg = blockIdx.x * 4 + wid;
  const int b = rg >> 11, n = rg & (kN - 1);
  const int j = nbr[n];
  const int j2 = nbr[j];
  const short8 xv = *reinterpret_cast<const short8*>(&xh[(size_t)rg * kC + lane * 8]);
  const short8 wv = *reinterpret_cast<const short8*>(&obuf[(size_t)(b * kN + j) * kNC + lane * 8]);
  float a = 0.f;
#pragma unroll
  for (int q = 0; q < 8; q++) a += bf2f((ushort)xv[q]) * bf2f((ushort)wv[q]);
#pragma unroll
  for (int off = 32; off; off >>= 1) a += __shfl_xor(a, off);
  const float s = a + g[b * kN + j] + bqbk[0] + rb[0];
  const float tt = s * kInvSqrtC;
  const float e = expf(tt);
  const float inv = 1.0f / (e + (float)(kN - 1));
  const float coef = (e - 1.0f) * inv;
  const short8 vv = *reinterpret_cast<const short8*>(&obuf[(size_t)(b * kN + j2) * kNC + kC + lane * 8]);
  const float4 s0 = *reinterpret_cast<const float4*>(&svo[b * kC + lane * 8]);
  const float4 s1 = *reinterpret_cast<const float4*>(&svo[b * kC + lane * 8 + 4]);
  const float4 b0 = *reinterpret_cast<const float4*>(&bo[lane * 8]);
  const float4 b1 = *reinterpret_cast<const float4*>(&bo[lane * 8 + 4]);
  float4 r0, r1;
  r0.x = s0.x * inv + bf2f((ushort)vv[0]) * coef + b0.x;
  r0.y = s0.y * inv + bf2f((ushort)vv[1]) * coef + b0.y;
  r0.z = s0.z * inv + bf2f((ushort)vv[2]) * coef + b0.z;
  r0.w = s0.w * inv + bf2f((ushort)vv[3]) * coef + b0.w;
  r1.x = s1.x * inv + bf2f((ushort)vv[4]) * coef + b1.x;
  r1.y = s1.y * inv + bf2f((ushort)vv[5]) * coef + b1.y;
  r1.z = s1.z * inv + bf2f((ushort)vv[6]) * coef + b1.z;
  r1.w = s1.w * inv + bf2f((ushort)vv[7]) * coef + b1.w;
  *reinterpret_cast<float4*>(&out[(size_t)rg * kC + lane * 8]) = r0;
  *reinterpret_cast<float4*>(&out[(size_t)rg * kC + lane * 8 + 4]) = r1;
}

extern "C" void kernel_launch(void* const* d_in, const int* in_sizes, int n_in,
                              void* d_out, int out_size, void* d_ws, size_t ws_size,
                              hipStream_t stream) {
  const float* x  = (const float*)d_in[0];
  const int* nbr  = (const int*)d_in[1];
  const float* Wq = (const float*)d_in[2];
  const float* bq = (const float*)d_in[3];
  const float* Wk = (const float*)d_in[4];
  const float* bk = (const float*)d_in[5];
  const float* Wv = (const float*)d_in[6];
  const float* bv = (const float*)d_in[7];
  const float* rb = (const float*)d_in[8];
  const float* Wo = (const float*)d_in[9];
  const float* bo = (const float*)d_in[10];
  float* out = (float*)d_out;

  char* ws = (char*)d_ws;
  size_t off = 0;
  auto alloc = [&](size_t bytes) -> void* {
    void* p = ws + off;
    off = (off + bytes + 255) & ~(size_t)255;
    return p;
  };
  ushort* xh    = (ushort*)alloc((size_t)kR * kC * 2);
  ushort* Bh    = (ushort*)alloc((size_t)kNC * kC * 2);
  ushort* obuf  = (ushort*)alloc((size_t)kR * kNC * 2);
  ushort* WqT   = (ushort*)alloc((size_t)kC * kC * 2);
  ushort* WkT   = (ushort*)alloc((size_t)kC * kC * 2);
  ushort* WvT   = (ushort*)alloc((size_t)kC * kC * 2);
  ushort* Woh   = (ushort*)alloc((size_t)kC * kC * 2);
  float* biascat = (float*)alloc(kNC * 4);
  float* vbq    = (float*)alloc(kC * 4);
  float* bqbk   = (float*)alloc(4);
  int*   cnt    = (int*)alloc(kN * 4);
  float* g      = (float*)alloc((size_t)kR * 4);
  float* svo    = (float*)alloc((size_t)kB * kC * 4);
  float* part   = (float*)alloc((size_t)kB * 32 * kC * 4);
  (void)ws_size; (void)n_in; (void)in_sizes; (void)out_size;

  castw_kernel<<<dim3(8, 8, 5), 256, 0, stream>>>(Wq, Wk, Wv, Wo, WqT, WkT, WvT, Woh, nbr, cnt);
  fold_kernel<<<dim3(8, 8, 3), 256, 0, stream>>>(WqT, WkT, Woh, WvT, Bh, bq, bk, bv, biascat, vbq, bqbk);
  castg_kernel<<<kR / 4, 256, 0, stream>>>(x, vbq, xh, g);
  mm_kernel<<<1024, 256, 0, stream>>>(xh, Bh, biascat, obuf);
  svo_part_kernel<<<dim3(2, 32, kB), 256, 0, stream>>>(obuf, cnt, part);
  svo_reduce_kernel<<<dim3(2, kB), 256, 0, stream>>>(part, svo);
  final_kernel<<<kR / 4, 256, 0, stream>>>(xh, obuf, svo, g, nbr, bqbk, rb, bo, out);
}